// Round 7
// baseline (510.171 us; speedup 1.0000x reference)
//
#include <hip/hip_runtime.h>
#include <hip/hip_bf16.h>
#include <stdint.h>

typedef __attribute__((ext_vector_type(8))) short short8;
typedef __attribute__((ext_vector_type(4))) float f32x4;
typedef __attribute__((ext_vector_type(4))) unsigned short us4;

#define DIMC 768
#define NTOK 32768
#define NPB 4096
#define HEADS 8
#define DH 96

__device__ __forceinline__ ushort f2bf(float f) {
    union { float f; uint32_t u; } c; c.f = f;
    uint32_t u = c.u;
    u += 0x7fffu + ((u >> 16) & 1u);
    return (ushort)(u >> 16);
}
__device__ __forceinline__ float bf2f(ushort h) {
    union { uint32_t u; float f; } c; c.u = ((uint32_t)h) << 16;
    return c.f;
}

__device__ __forceinline__ void gload_lds16(const void* g, void* l) {
    __builtin_amdgcn_global_load_lds(
        (const __attribute__((address_space(1))) void*)g,
        (__attribute__((address_space(3))) void*)l, 16, 0, 0);
}

// =====================================================================
// 256x256-tile BK=64 GEMM core, 8 waves (2Mx4N), 4 phases x 16 MFMA.
// LDS 128 KiB: A[2][256][64], B[2][256][64] bf16, 128 B rows.
// Swizzle: byte ^= ((byte>>7)&7)<<4  (row&7 -> distinct 16B slot; involution;
// stage = linear dest + inverse-swizzled global src, read = swizzled addr).
// Row stride in global memory fixed at 1536 B (= 768 ch * 2 B).
// Stage plan (race-free):
//   PH1(t): stage A(t+1)->buf c^1   [A c^1 reads drained pre-PH4bar(t-1)]
//   PH3(t): stage B(t+2)->buf c     [B c reads drained pre-PH2bar(t)]
//   PH4(t): vmcnt(4) counted (A(t+1),B(t+1) landed; B(t+2) in flight).
// lgkm(0) placed PRE-barrier in PH2/PH4 (publishes buffer free), POST-barrier
// in PH1/PH3 (normal consume).
// =====================================================================
__device__ __forceinline__ void gemm256_bk64(
    const char* aglob, const char* bglob, char* lds, f32x4 (&acc)[8][4]) {
    const int tid = threadIdx.x;
    const int lane = tid & 63, wid = tid >> 6;
    const int wr = wid >> 2, wc = wid & 3;
    const int k8 = lane >> 4, l15 = lane & 15;

    int Ls[4], srs[4], scs[4];
#pragma unroll
    for (int u = 0; u < 4; u++) {
        int L = tid * 16 + u * 8192;
        int S = L ^ (((L >> 7) & 7) << 4);
        Ls[u] = L; srs[u] = S >> 7; scs[u] = S & 127;
    }
    int aoff[2][8], boff[2][4];
#pragma unroll
    for (int ks = 0; ks < 2; ks++) {
#pragma unroll
        for (int m = 0; m < 8; m++) {
            int row = wr * 128 + m * 16 + l15;
            int o = row * 128 + ks * 64 + k8 * 16;
            aoff[ks][m] = o ^ (((o >> 7) & 7) << 4);
        }
#pragma unroll
        for (int n = 0; n < 4; n++) {
            int row = wc * 64 + n * 16 + l15;
            int o = row * 128 + ks * 64 + k8 * 16;
            boff[ks][n] = o ^ (((o >> 7) & 7) << 4);
        }
    }

#define STG_A64(kt, c) do {                                              \
        const char* ak_ = aglob + (size_t)(kt) * 128;                    \
        char* al_ = lds + (c) * 32768;                                   \
        _Pragma("unroll")                                                \
        for (int u = 0; u < 4; u++)                                      \
            gload_lds16(ak_ + (size_t)srs[u] * 1536 + scs[u], al_ + Ls[u]); \
    } while (0)
#define STG_B64(kt, c) do {                                              \
        const char* bk_ = bglob + (size_t)(kt) * 128;                    \
        char* bl_ = lds + 65536 + (c) * 32768;                           \
        _Pragma("unroll")                                                \
        for (int u = 0; u < 4; u++)                                      \
            gload_lds16(bk_ + (size_t)srs[u] * 1536 + scs[u], bl_ + Ls[u]); \
    } while (0)
#define MFMA16(mb, AF, BF)                                               \
    __builtin_amdgcn_s_setprio(1);                                       \
    _Pragma("unroll")                                                    \
    for (int m = 0; m < 4; m++)                                          \
        _Pragma("unroll")                                                \
        for (int n = 0; n < 4; n++)                                      \
            acc[(mb) + m][n] = __builtin_amdgcn_mfma_f32_16x16x32_bf16(  \
                AF[m], BF[n], acc[(mb) + m][n], 0, 0, 0);                \
    __builtin_amdgcn_s_setprio(0);

    STG_A64(0, 0); STG_B64(0, 0); STG_B64(1, 1);   // 12 vm ops
    asm volatile("s_waitcnt vmcnt(4)" ::: "memory"); // A0,B0 landed; B1 in flight
    asm volatile("s_barrier" ::: "memory");

#pragma unroll 2
    for (int t = 0; t < 12; ++t) {
        const int c = t & 1;
        const char* ap = lds + c * 32768;
        const char* bp = lds + 65536 + c * 32768;
        short8 af[4], bf0[4], bf1[4];
        // ---- PH1: B ks0 + A ks0 m0-3; stage A(t+1) ----
#pragma unroll
        for (int n = 0; n < 4; n++) bf0[n] = *(const short8*)(bp + boff[0][n]);
#pragma unroll
        for (int m = 0; m < 4; m++) af[m] = *(const short8*)(ap + aoff[0][m]);
        if (t + 1 < 12) STG_A64(t + 1, c ^ 1);
        asm volatile("s_barrier" ::: "memory");
        asm volatile("s_waitcnt lgkmcnt(0)" ::: "memory");
        __builtin_amdgcn_sched_barrier(0);
        MFMA16(0, af, bf0)
        // ---- PH2: A ks0 m4-7 + B ks1 (early); pre-bar drain ----
#pragma unroll
        for (int m = 0; m < 4; m++) af[m] = *(const short8*)(ap + aoff[0][4 + m]);
#pragma unroll
        for (int n = 0; n < 4; n++) bf1[n] = *(const short8*)(bp + boff[1][n]);
        asm volatile("s_waitcnt lgkmcnt(0)" ::: "memory");  // B-buf c reads done
        __builtin_amdgcn_sched_barrier(0);
        asm volatile("s_barrier" ::: "memory");
        MFMA16(4, af, bf0)
        // ---- PH3: A ks1 m0-3; stage B(t+2)->buf c ----
#pragma unroll
        for (int m = 0; m < 4; m++) af[m] = *(const short8*)(ap + aoff[1][m]);
        if (t + 2 < 12) STG_B64(t + 2, c);
        asm volatile("s_barrier" ::: "memory");
        asm volatile("s_waitcnt lgkmcnt(0)" ::: "memory");
        __builtin_amdgcn_sched_barrier(0);
        MFMA16(0, af, bf1)
        // ---- PH4: A ks1 m4-7; counted vmcnt; pre-bar drain ----
#pragma unroll
        for (int m = 0; m < 4; m++) af[m] = *(const short8*)(ap + aoff[1][4 + m]);
        if (t + 2 < 12) asm volatile("s_waitcnt vmcnt(4)" ::: "memory");
        else            asm volatile("s_waitcnt vmcnt(0)" ::: "memory");
        asm volatile("s_waitcnt lgkmcnt(0)" ::: "memory");  // A-buf c reads done
        __builtin_amdgcn_sched_barrier(0);
        asm volatile("s_barrier" ::: "memory");
        MFMA16(4, af, bf1)
    }
#undef STG_A64
#undef STG_B64
#undef MFMA16
}

// ---------------- weight prep: bf16 casts, vectorized ----------------
__global__ __launch_bounds__(256) void prep_w_kernel(
    const float* __restrict__ qw, const float* __restrict__ pw,
    ushort* __restrict__ qwb, ushort* __restrict__ pwb) {
    int i4 = (blockIdx.x * 256 + threadIdx.x) * 4;
    if (i4 < 3 * DIMC * DIMC) {
        float4 w = *(const float4*)&qw[i4];
        us4 o;
        o[0] = f2bf(w.x); o[1] = f2bf(w.y); o[2] = f2bf(w.z); o[3] = f2bf(w.w);
        *(us4*)&qwb[i4] = o;
    }
    if (i4 < DIMC * DIMC) {
        float4 w = *(const float4*)&pw[i4];
        us4 o;
        o[0] = f2bf(w.x); o[1] = f2bf(w.y); o[2] = f2bf(w.z); o[3] = f2bf(w.w);
        *(us4*)&pwb[i4] = o;
    }
}

// ---------------- LayerNorm + cast: xb = bf16(ln(x)*g + b) ----------------
__global__ __launch_bounds__(256) void ln_cvt_kernel(
    const float* __restrict__ x, const float* __restrict__ g,
    const float* __restrict__ b, ushort* __restrict__ xb) {
    int t = blockIdx.x * 4 + (threadIdx.x >> 6);
    int lane = threadIdx.x & 63;
    const float* xr = x + (size_t)t * DIMC;
    float4 v[3];
    float s = 0.f, s2 = 0.f;
#pragma unroll
    for (int u = 0; u < 3; u++) {
        v[u] = *(const float4*)&xr[u * 256 + lane * 4];
        s  += v[u].x + v[u].y + v[u].z + v[u].w;
        s2 += v[u].x * v[u].x + v[u].y * v[u].y + v[u].z * v[u].z + v[u].w * v[u].w;
    }
#pragma unroll
    for (int off = 32; off > 0; off >>= 1) {
        s  += __shfl_down(s, off);
        s2 += __shfl_down(s2, off);
    }
    s = __shfl(s, 0);
    s2 = __shfl(s2, 0);
    float mean = s * (1.0f / DIMC);
    float rstd = rsqrtf(s2 * (1.0f / DIMC) - mean * mean + 1e-5f);
    ushort* xo = xb + (size_t)t * DIMC;
#pragma unroll
    for (int u = 0; u < 3; u++) {
        float4 gv = *(const float4*)&g[u * 256 + lane * 4];
        float4 bv = *(const float4*)&b[u * 256 + lane * 4];
        us4 o;
        o[0] = f2bf((v[u].x - mean) * rstd * gv.x + bv.x);
        o[1] = f2bf((v[u].y - mean) * rstd * gv.y + bv.y);
        o[2] = f2bf((v[u].z - mean) * rstd * gv.z + bv.z);
        o[3] = f2bf((v[u].w - mean) * rstd * gv.w + bv.w);
        *(us4*)&xo[u * 256 + lane * 4] = o;
    }
}

// ---------------- QKV GEMM: 256x256 BK=64 pipelined ----------------
__global__ __launch_bounds__(512) void gemm_qkv_kernel(
    const ushort* __restrict__ xb, const ushort* __restrict__ wb,
    ushort* __restrict__ qb, ushort* __restrict__ kb, ushort* __restrict__ vb) {
    __shared__ __align__(16) char lds[131072];
    int orig = blockIdx.x;                   // 0..1151
    int wg = (orig & 7) * 144 + (orig >> 3);
    int nt = wg % 9, mt = wg / 9;
    int m0 = mt * 256, n0 = nt * 256;
    f32x4 acc[8][4] = {};
    gemm256_bk64((const char*)(xb + (size_t)m0 * DIMC),
                 (const char*)(wb + (size_t)n0 * DIMC), lds, acc);

    int tid = threadIdx.x, lane = tid & 63, wid = tid >> 6;
    int wr = wid >> 2, wc = wid & 3;
    int k8 = lane >> 4, l15 = lane & 15;
    int seg = n0 / DIMC;                     // 0=q, 1=k, 2=v (no straddle)
#pragma unroll
    for (int m8 = 0; m8 < 8; m8++) {
        int r0 = m0 + wr * 128 + m8 * 16 + k8 * 4;
        int b_ = r0 >> 12, nn = r0 & (NPB - 1);
#pragma unroll
        for (int n = 0; n < 4; n++) {
            int o = n0 + wc * 64 + n * 16 + l15;
            f32x4 a = acc[m8][n];
            if (seg == 2) {
                int oL = o - 2 * DIMC;
#pragma unroll
                for (int qq = 0; qq < 4; qq++)
                    vb[(size_t)(r0 + qq) * DIMC + oL] = f2bf(a[qq]);
            } else {
                int oL = o - seg * DIMC;
                int h = oL / DH, d = oL - h * DH;
                us4 pk;
#pragma unroll
                for (int qq = 0; qq < 4; qq++) pk[qq] = f2bf(a[qq]);
                *(us4*)((seg ? kb : qb) +
                        ((size_t)(b_ * HEADS + h) * DH + d) * NPB + nn) = pk;
            }
        }
    }
}

// ---------------- attn partial: S[ch][bh][96][96] + q/k sumsq partials -----
// grid (64, 8), 9 waves; q sumsq by waves wid%3==0, k sumsq by wid<3
__global__ __launch_bounds__(576) void attn_qk_kernel(
    const ushort* __restrict__ qb, const ushort* __restrict__ kb,
    float* __restrict__ S, float* __restrict__ S2) {
    int bh = blockIdx.x, ch = blockIdx.y;
    int tid = threadIdx.x, wid = tid >> 6, lane = tid & 63;
    int wr = wid / 3, wc = wid - wr * 3;
    int k8 = lane >> 4, l15 = lane & 15;
    const ushort* qrow = qb + (size_t)bh * DH * NPB + ch * 512;
    const ushort* krow = kb + (size_t)bh * DH * NPB + ch * 512;
    bool doq = (wc == 0), dok = (wr == 0);
    f32x4 acc[2][2] = {};
    float sq[2] = {0.f, 0.f}, sk[2] = {0.f, 0.f};
    for (int n = 0; n < 512; n += 32) {
        short8 a[2], b[2];
#pragma unroll
        for (int i = 0; i < 2; i++)
            a[i] = *(const short8*)&qrow[(size_t)(wr * 32 + i * 16 + l15) * NPB + n + k8 * 8];
#pragma unroll
        for (int j = 0; j < 2; j++)
            b[j] = *(const short8*)&krow[(size_t)(wc * 32 + j * 16 + l15) * NPB + n + k8 * 8];
        if (doq) {
#pragma unroll
            for (int i = 0; i < 2; i++)
#pragma unroll
                for (int u = 0; u < 8; u++) {
                    float f = bf2f((ushort)a[i][u]); sq[i] += f * f;
                }
        }
        if (dok) {
#pragma unroll
            for (int j = 0; j < 2; j++)
#pragma unroll
                for (int u = 0; u < 8; u++) {
                    float f = bf2f((ushort)b[j][u]); sk[j] += f * f;
                }
        }
#pragma unroll
        for (int i = 0; i < 2; i++)
#pragma unroll
            for (int j = 0; j < 2; j++)
                acc[i][j] = __builtin_amdgcn_mfma_f32_16x16x32_bf16(a[i], b[j], acc[i][j], 0, 0, 0);
    }
    float* S2o = S2 + ((size_t)ch * 64 + bh) * 192;
    if (doq) {
#pragma unroll
        for (int i = 0; i < 2; i++) {
            float v = sq[i];
            v += __shfl_xor(v, 16); v += __shfl_xor(v, 32);
            if (lane < 16) S2o[wr * 32 + i * 16 + l15] = v;
        }
    }
    if (dok) {
#pragma unroll
        for (int j = 0; j < 2; j++) {
            float v = sk[j];
            v += __shfl_xor(v, 16); v += __shfl_xor(v, 32);
            if (lane < 16) S2o[96 + wc * 32 + j * 16 + l15] = v;
        }
    }
    float* So = S + ((size_t)ch * 64 + bh) * (DH * DH);
#pragma unroll
    for (int i = 0; i < 2; i++)
#pragma unroll
        for (int j = 0; j < 2; j++) {
            int e = wc * 32 + j * 16 + l15;
#pragma unroll
            for (int qq = 0; qq < 4; qq++) {
                int d = wr * 32 + i * 16 + k8 * 4 + qq;
                So[d * DH + e] = acc[i][j][qq];
            }
        }
}

// ---------------- attn softmax: reduce chunks + sumsq, write attn^T --------
// grid (64, 3), 192 threads: 32 rows x 6 col-groups of 16
__global__ __launch_bounds__(192) void attn_soft_kernel(
    const float* __restrict__ S, const float* __restrict__ S2,
    const float* __restrict__ temp, ushort* __restrict__ attnT) {
    int bh = blockIdx.x, ds0 = blockIdx.y * 32;
    int tid = threadIdx.x, r = tid & 31, p = tid >> 5;
    int d = ds0 + r;
    __shared__ float rkv[96];
    if (tid < 96) {
        float sum = 0.f;
#pragma unroll 1
        for (int ch = 0; ch < 8; ch++)
            sum += S2[((size_t)ch * 64 + bh) * 192 + 96 + tid];
        rkv[tid] = 1.0f / fmaxf(sqrtf(sum), 1e-12f);
    }
    float sqd = 0.f;
#pragma unroll 1
    for (int ch = 0; ch < 8; ch++)
        sqd += S2[((size_t)ch * 64 + bh) * 192 + d];
    float rqd = 1.0f / fmaxf(sqrtf(sqd), 1e-12f);
    float4 v[4] = {};
#pragma unroll 1
    for (int ch = 0; ch < 8; ch++) {
        const float* So = S + (((size_t)ch * 64 + bh) * DH + d) * DH + p * 16;
#pragma unroll
        for (int u = 0; u < 4; u++) {
            float4 w = *(const float4*)&So[u * 4];
            v[u].x += w.x; v[u].y += w.y; v[u].z += w.z; v[u].w += w.w;
        }
    }
    __syncthreads();   // rkv ready
    float sd = rqd * temp[bh & (HEADS - 1)];
#pragma unroll
    for (int u = 0; u < 4; u++) {
        int e0 = p * 16 + u * 4;
        v[u].x *= sd * rkv[e0]; v[u].y *= sd * rkv[e0 + 1];
        v[u].z *= sd * rkv[e0 + 2]; v[u].w *= sd * rkv[e0 + 3];
    }
    __shared__ float red[32][8], red2[32][8];
    float lm = -3.4e38f;
#pragma unroll
    for (int u = 0; u < 4; u++)
        lm = fmaxf(lm, fmaxf(fmaxf(v[u].x, v[u].y), fmaxf(v[u].z, v[u].w)));
    red[r][p] = lm;
    __syncthreads();
    float m = red[r][0];
#pragma unroll
    for (int u = 1; u < 6; u++) m = fmaxf(m, red[r][u]);
    float s = 0.f;
#pragma unroll
    for (int u = 0; u < 4; u++) {
        v[u].x = __expf(v[u].x - m); v[u].y = __expf(v[u].y - m);
        v[u].z = __expf(v[u].z - m); v[u].w = __expf(v[u].w - m);
        s += v[u].x + v[u].y + v[u].z + v[u].w;
    }
    red2[r][p] = s;
    __syncthreads();
    float tot = red2[r][0];
#pragma unroll
    for (int u = 1; u < 6; u++) tot += red2[r][u];
    float inv = 1.0f / tot;
    // transposed store: attnT[bh][e][d]
    ushort* ao = attnT + (size_t)bh * (DH * DH) + d;
#pragma unroll
    for (int u = 0; u < 4; u++) {
        int e0 = p * 16 + u * 4;
        ao[(e0 + 0) * DH] = f2bf(v[u].x * inv);
        ao[(e0 + 1) * DH] = f2bf(v[u].y * inv);
        ao[(e0 + 2) * DH] = f2bf(v[u].z * inv);
        ao[(e0 + 3) * DH] = f2bf(v[u].w * inv);
    }
}

// ---------------- W2 prep: W2[b][o][h*96+e] = sum_d pw[o][h*96+d]*attn[d][e]
// grid (64, 3): (bh, o-tile of 256); 4 waves, each 64 o-rows x 96 e
__global__ __launch_bounds__(256) void w2prep_kernel(
    const ushort* __restrict__ pwb, const ushort* __restrict__ attnT,
    ushort* __restrict__ W2) {
    int bh = blockIdx.x, o0 = blockIdx.y * 256;
    int b_ = bh >> 3, h = bh & 7;
    int tid = threadIdx.x, wid = tid >> 6, lane = tid & 63;
    int k8 = lane >> 4, l15 = lane & 15;
    const ushort* at = attnT + (size_t)bh * (DH * DH);
    f32x4 acc[4][6] = {};
#pragma unroll
    for (int kk = 0; kk < DH; kk += 32) {
        short8 af[4], bf[6];
#pragma unroll
        for (int m = 0; m < 4; m++)
            af[m] = *(const short8*)&pwb[(size_t)(o0 + wid * 64 + m * 16 + l15) * DIMC
                                         + h * DH + kk + k8 * 8];
#pragma unroll
        for (int n = 0; n < 6; n++)
            bf[n] = *(const short8*)&at[(n * 16 + l15) * DH + kk + k8 * 8];
#pragma unroll
        for (int m = 0; m < 4; m++)
#pragma unroll
            for (int n = 0; n < 6; n++)
                acc[m][n] = __builtin_amdgcn_mfma_f32_16x16x32_bf16(af[m], bf[n], acc[m][n], 0, 0, 0);
    }
    ushort* wo = W2 + (size_t)b_ * DIMC * DIMC + (size_t)h * DH;
#pragma unroll
    for (int m = 0; m < 4; m++) {
        int orow = o0 + wid * 64 + m * 16 + k8 * 4;
#pragma unroll
        for (int n = 0; n < 6; n++) {
            int e = n * 16 + l15;
#pragma unroll
            for (int qq = 0; qq < 4; qq++)
                wo[(size_t)(orow + qq) * DIMC + e] = f2bf(acc[m][n][qq]);
        }
    }
}

// ---------------- vproj: out = g1*(v·W2[b]^T + pb) + x  (256x256 BK=64) ----
__global__ __launch_bounds__(512) void vproj_kernel(
    const ushort* __restrict__ vb, const ushort* __restrict__ W2,
    const float* __restrict__ pb, const float* __restrict__ g1,
    const float* __restrict__ x, float* __restrict__ out) {
    __shared__ __align__(16) char lds[131072];
    int orig = blockIdx.x;                   // 0..383
    int wg = (orig & 7) * 48 + (orig >> 3);
    int b_ = wg / 48, rem = wg % 48, mt = rem / 3, ntl = rem % 3;
    int tok0 = b_ * NPB + mt * 256, o0 = ntl * 256;
    f32x4 acc[8][4] = {};
    gemm256_bk64((const char*)(vb + (size_t)tok0 * DIMC),
                 (const char*)(W2 + (size_t)b_ * DIMC * DIMC + (size_t)o0 * DIMC),
                 lds, acc);

    int tid = threadIdx.x, lane = tid & 63, wid = tid >> 6;
    int wr = wid >> 2, wc = wid & 3;
    int k8 = lane >> 4, l15 = lane & 15;
#pragma unroll
    for (int m8 = 0; m8 < 8; m8++) {
        int r0 = tok0 + wr * 128 + m8 * 16 + k8 * 4;
#pragma unroll
        for (int n = 0; n < 4; n++) {
            int o = o0 + wc * 64 + n * 16 + l15;
            float pbo = pb[o], g1o = g1[o];
            f32x4 a = acc[m8][n];
#pragma unroll
            for (int qq = 0; qq < 4; qq++) {
                size_t idx = (size_t)(r0 + qq) * DIMC + o;
                out[idx] = g1o * (a[qq] + pbo) + x[idx];
            }
        }
    }
}

extern "C" void kernel_launch(void* const* d_in, const int* in_sizes, int n_in,
                              void* d_out, int out_size, void* d_ws, size_t ws_size,
                              hipStream_t stream) {
    const float* x     = (const float*)d_in[0];
    const float* qkvw  = (const float*)d_in[1];
    const float* projw = (const float*)d_in[2];
    const float* projb = (const float*)d_in[3];
    const float* lng   = (const float*)d_in[4];
    const float* lnb   = (const float*)d_in[5];
    const float* temp  = (const float*)d_in[6];
    const float* g1    = (const float*)d_in[7];
    float* out = (float*)d_out;

    char* w = (char*)d_ws;
    ushort* qb    = (ushort*)(w + 0);            // 50,331,648  [B,H,dh,N]
    ushort* kb    = (ushort*)(w + 50331648);     // 50,331,648
    ushort* vb    = (ushort*)(w + 100663296);    // 50,331,648  [T, C] token-major
    ushort* qwb   = (ushort*)(w + 150994944);    // 3,538,944  (dead after qkv)
    ushort* pwb   = (ushort*)(w + 154533888);    // 1,179,648
    float*  S2    = (float*)(w + 155713536);     // 393,216 sumsq partials
    ushort* attnT = qwb;                         // 1,179,648 (aliases dead qwb)
    ushort* W2    = qb;                          // 9,437,184 (aliases dead qb)
    ushort* xb    = (ushort*)d_out;              // LN output (dead before vproj)
    float*  S     = (float*)((char*)d_out + 50331648);  // 18.9 MB attn partials

    hipLaunchKernelGGL(prep_w_kernel, dim3(1728), dim3(256), 0, stream,
                       qkvw, projw, qwb, pwb);
    hipLaunchKernelGGL(ln_cvt_kernel, dim3(8192), dim3(256), 0, stream,
                       x, lng, lnb, xb);
    hipLaunchKernelGGL(gemm_qkv_kernel, dim3(1152), dim3(512), 0, stream,
                       xb, qwb, qb, kb, vb);
    hipLaunchKernelGGL(attn_qk_kernel, dim3(64, 8), dim3(576), 0, stream,
                       qb, kb, S, S2);
    hipLaunchKernelGGL(attn_soft_kernel, dim3(64, 3), dim3(192), 0, stream,
                       S, S2, temp, attnT);
    hipLaunchKernelGGL(w2prep_kernel, dim3(64, 3), dim3(256), 0, stream,
                       pwb, attnT, W2);
    hipLaunchKernelGGL(vproj_kernel, dim3(384), dim3(512), 0, stream,
                       vb, W2, projb, g1, x, out);
}

// Round 8
// 321.993 us; speedup vs baseline: 1.5844x; 1.5844x over previous
//
#include <hip/hip_runtime.h>
#include <hip/hip_bf16.h>
#include <stdint.h>

typedef __attribute__((ext_vector_type(8))) short short8;
typedef __attribute__((ext_vector_type(4))) float f32x4;
typedef __attribute__((ext_vector_type(4))) unsigned short us4;

#define DIMC 768
#define NTOK 32768
#define NPB 4096
#define HEADS 8
#define DH 96

__device__ __forceinline__ ushort f2bf(float f) {
    union { float f; uint32_t u; } c; c.f = f;
    uint32_t u = c.u;
    u += 0x7fffu + ((u >> 16) & 1u);
    return (ushort)(u >> 16);
}
__device__ __forceinline__ float bf2f(ushort h) {
    union { uint32_t u; float f; } c; c.u = ((uint32_t)h) << 16;
    return c.f;
}

__device__ __forceinline__ void gload_lds16(const void* g, void* l) {
    __builtin_amdgcn_global_load_lds(
        (const __attribute__((address_space(1))) void*)g,
        (__attribute__((address_space(3))) void*)l, 16, 0, 0);
}

// =====================================================================
// 256x256-tile BK=32 GEMM core, 8 waves, 4 phases per K-tile (R6-measured:
// 148us qkv, MfmaUtil 33%, 0 bank conflicts, 64 KiB LDS -> 2 blocks/CU).
// LDS: A[2][256][32], B[2][256][32] bf16, 64 B rows,
// st_16x32 swizzle (byte ^= ((byte>>9)&1)<<5), linear gload_lds dest +
// pre-swizzled global source + swizzled ds_read.
// Stage plan (race-free):
//   PH1(t): stage A(t+1) -> buf t^1   (A there drained pre-bar4(t-1))
//   PH3(t): stage B(t+2) -> buf t     (B there drained by bar2(t))
// vmcnt(2) at PH4 confirms A(t+1)/B(t+1) while B(t+2) stays in flight.
// =====================================================================
__device__ __forceinline__ void gemm256_core(
    const char* aglob, const char* bglob, char* lds, f32x4 (&acc)[8][4]) {
    const int tid = threadIdx.x;
    const int lane = tid & 63, wid = tid >> 6;
    const int wr = wid >> 2, wc = wid & 3;
    const int k8 = lane >> 4, l15 = lane & 15;

    const int L0 = tid * 16, L1 = (512 + tid) * 16;
    const int S0 = L0 ^ (((L0 >> 9) & 1) << 5);
    const int S1 = L1 ^ (((L1 >> 9) & 1) << 5);
    const int sr0 = S0 >> 6, sc0 = S0 & 63;
    const int sr1 = S1 >> 6, sc1 = S1 & 63;

    int aoff[8], boff[4];
#pragma unroll
    for (int m = 0; m < 8; m++) {
        int row = wr * 128 + m * 16 + l15;
        int o = row * 64 + k8 * 16;
        aoff[m] = o ^ (((o >> 9) & 1) << 5);
    }
#pragma unroll
    for (int n = 0; n < 4; n++) {
        int row = wc * 64 + n * 16 + l15;
        int o = row * 64 + k8 * 16;
        boff[n] = o ^ (((o >> 9) & 1) << 5);
    }

#define STG_A(kt, c) do {                                     \
        const char* ak_ = aglob + (size_t)(kt) * 64;          \
        char* al_ = lds + (c) * 16384;                        \
        gload_lds16(ak_ + sr0 * 1536 + sc0, al_ + L0);        \
        gload_lds16(ak_ + sr1 * 1536 + sc1, al_ + L1);        \
    } while (0)
#define STG_B(kt, c) do {                                     \
        const char* bk_ = bglob + (size_t)(kt) * 64;          \
        char* bl_ = lds + 32768 + (c) * 16384;                \
        gload_lds16(bk_ + sr0 * 1536 + sc0, bl_ + L0);        \
        gload_lds16(bk_ + sr1 * 1536 + sc1, bl_ + L1);        \
    } while (0)
#define MFMA_PAIR(ma, mb)                                                          \
    __builtin_amdgcn_s_setprio(1);                                                 \
    _Pragma("unroll")                                                              \
    for (int n = 0; n < 4; n++)                                                    \
        acc[ma][n] = __builtin_amdgcn_mfma_f32_16x16x32_bf16(af[ma], bf[n], acc[ma][n], 0, 0, 0); \
    _Pragma("unroll")                                                              \
    for (int n = 0; n < 4; n++)                                                    \
        acc[mb][n] = __builtin_amdgcn_mfma_f32_16x16x32_bf16(af[mb], bf[n], acc[mb][n], 0, 0, 0); \
    __builtin_amdgcn_s_setprio(0);

    // prologue: tile0 both operands + B(1); A(1) comes from PH1(0)
    STG_A(0, 0); STG_B(0, 0); STG_B(1, 1);
    asm volatile("s_waitcnt vmcnt(2)" ::: "memory");   // A(0),B(0) landed; B(1) in flight
    asm volatile("s_barrier" ::: "memory");

#pragma unroll 2
    for (int t = 0; t < 24; ++t) {
        const int c = t & 1;
        const char* ap = lds + c * 16384;
        const char* bp = lds + 32768 + c * 16384;
        short8 af[8], bf[4];
        // ---- PH1 ----
#pragma unroll
        for (int n = 0; n < 4; n++) bf[n] = *(const short8*)(bp + boff[n]);
#pragma unroll
        for (int m = 0; m < 4; m++) af[m] = *(const short8*)(ap + aoff[m]);
        if (t + 1 < 24) STG_A(t + 1, c ^ 1);
        asm volatile("s_barrier" ::: "memory");
        asm volatile("s_waitcnt lgkmcnt(2)" ::: "memory");
        __builtin_amdgcn_sched_barrier(0);
        MFMA_PAIR(0, 1)
        // ---- PH2 ----
#pragma unroll
        for (int m = 4; m < 8; m++) af[m] = *(const short8*)(ap + aoff[m]);
        asm volatile("s_barrier" ::: "memory");
        asm volatile("s_waitcnt lgkmcnt(4)" ::: "memory");
        __builtin_amdgcn_sched_barrier(0);
        MFMA_PAIR(2, 3)
        // ---- PH3 ----
        if (t + 2 < 24) STG_B(t + 2, c);
        asm volatile("s_barrier" ::: "memory");
        asm volatile("s_waitcnt lgkmcnt(2)" ::: "memory");
        __builtin_amdgcn_sched_barrier(0);
        MFMA_PAIR(4, 5)
        // ---- PH4 ----
        if (t + 2 < 24) asm volatile("s_waitcnt vmcnt(2)" ::: "memory");
        else            asm volatile("s_waitcnt vmcnt(0)" ::: "memory");
        asm volatile("s_waitcnt lgkmcnt(0)" ::: "memory");  // A-region free as of next bar
        __builtin_amdgcn_sched_barrier(0);
        asm volatile("s_barrier" ::: "memory");
        MFMA_PAIR(6, 7)
    }
#undef STG_A
#undef STG_B
#undef MFMA_PAIR
}

// ---------------- weight prep: bf16 casts, vectorized ----------------
__global__ __launch_bounds__(256) void prep_w_kernel(
    const float* __restrict__ qw, const float* __restrict__ pw,
    ushort* __restrict__ qwb, ushort* __restrict__ pwb) {
    int i4 = (blockIdx.x * 256 + threadIdx.x) * 4;
    if (i4 < 3 * DIMC * DIMC) {
        float4 w = *(const float4*)&qw[i4];
        us4 o;
        o[0] = f2bf(w.x); o[1] = f2bf(w.y); o[2] = f2bf(w.z); o[3] = f2bf(w.w);
        *(us4*)&qwb[i4] = o;
    }
    if (i4 < DIMC * DIMC) {
        float4 w = *(const float4*)&pw[i4];
        us4 o;
        o[0] = f2bf(w.x); o[1] = f2bf(w.y); o[2] = f2bf(w.z); o[3] = f2bf(w.w);
        *(us4*)&pwb[i4] = o;
    }
}

// ---------------- LayerNorm + cast: xb = bf16(ln(x)*g + b) ----------------
__global__ __launch_bounds__(256) void ln_cvt_kernel(
    const float* __restrict__ x, const float* __restrict__ g,
    const float* __restrict__ b, ushort* __restrict__ xb) {
    int t = blockIdx.x * 4 + (threadIdx.x >> 6);
    int lane = threadIdx.x & 63;
    const float* xr = x + (size_t)t * DIMC;
    float4 v[3];
    float s = 0.f, s2 = 0.f;
#pragma unroll
    for (int u = 0; u < 3; u++) {
        v[u] = *(const float4*)&xr[u * 256 + lane * 4];
        s  += v[u].x + v[u].y + v[u].z + v[u].w;
        s2 += v[u].x * v[u].x + v[u].y * v[u].y + v[u].z * v[u].z + v[u].w * v[u].w;
    }
#pragma unroll
    for (int off = 32; off > 0; off >>= 1) {
        s  += __shfl_down(s, off);
        s2 += __shfl_down(s2, off);
    }
    s = __shfl(s, 0);
    s2 = __shfl(s2, 0);
    float mean = s * (1.0f / DIMC);
    float rstd = rsqrtf(s2 * (1.0f / DIMC) - mean * mean + 1e-5f);
    ushort* xo = xb + (size_t)t * DIMC;
#pragma unroll
    for (int u = 0; u < 3; u++) {
        float4 gv = *(const float4*)&g[u * 256 + lane * 4];
        float4 bv = *(const float4*)&b[u * 256 + lane * 4];
        us4 o;
        o[0] = f2bf((v[u].x - mean) * rstd * gv.x + bv.x);
        o[1] = f2bf((v[u].y - mean) * rstd * gv.y + bv.y);
        o[2] = f2bf((v[u].z - mean) * rstd * gv.z + bv.z);
        o[3] = f2bf((v[u].w - mean) * rstd * gv.w + bv.w);
        *(us4*)&xo[u * 256 + lane * 4] = o;
    }
}

// ---------------- QKV GEMM: 256x256 4-phase pipelined ----------------
__global__ __launch_bounds__(512) void gemm_qkv_kernel(
    const ushort* __restrict__ xb, const ushort* __restrict__ wb,
    ushort* __restrict__ qb, ushort* __restrict__ kb, ushort* __restrict__ vb) {
    __shared__ __align__(16) char lds[65536];
    int orig = blockIdx.x;                   // 0..1151
    int wg = (orig & 7) * 144 + (orig >> 3);
    int nt = wg % 9, mt = wg / 9;
    int m0 = mt * 256, n0 = nt * 256;
    f32x4 acc[8][4] = {};
    gemm256_core((const char*)(xb + (size_t)m0 * DIMC),
                 (const char*)(wb + (size_t)n0 * DIMC), lds, acc);

    int tid = threadIdx.x, lane = tid & 63, wid = tid >> 6;
    int wr = wid >> 2, wc = wid & 3;
    int k8 = lane >> 4, l15 = lane & 15;
    int seg = n0 / DIMC;                     // 0=q, 1=k, 2=v (no straddle)
#pragma unroll
    for (int m8 = 0; m8 < 8; m8++) {
        int r0 = m0 + wr * 128 + m8 * 16 + k8 * 4;
        int b_ = r0 >> 12, nn = r0 & (NPB - 1);
#pragma unroll
        for (int n = 0; n < 4; n++) {
            int o = n0 + wc * 64 + n * 16 + l15;
            f32x4 a = acc[m8][n];
            if (seg == 2) {
                int oL = o - 2 * DIMC;
#pragma unroll
                for (int qq = 0; qq < 4; qq++)
                    vb[(size_t)(r0 + qq) * DIMC + oL] = f2bf(a[qq]);
            } else {
                int oL = o - seg * DIMC;
                int h = oL / DH, d = oL - h * DH;
                us4 pk;
#pragma unroll
                for (int qq = 0; qq < 4; qq++) pk[qq] = f2bf(a[qq]);
                *(us4*)((seg ? kb : qb) +
                        ((size_t)(b_ * HEADS + h) * DH + d) * NPB + nn) = pk;
            }
        }
    }
}

// ---------------- attn partial: S[ch][bh][96][96] + q/k sumsq partials -----
// grid (64, 8), 9 waves; q sumsq by waves wc==0, k sumsq by wr==0
__global__ __launch_bounds__(576) void attn_qk_kernel(
    const ushort* __restrict__ qb, const ushort* __restrict__ kb,
    float* __restrict__ S, float* __restrict__ S2) {
    int bh = blockIdx.x, ch = blockIdx.y;
    int tid = threadIdx.x, wid = tid >> 6, lane = tid & 63;
    int wr = wid / 3, wc = wid - wr * 3;
    int k8 = lane >> 4, l15 = lane & 15;
    const ushort* qrow = qb + (size_t)bh * DH * NPB + ch * 512;
    const ushort* krow = kb + (size_t)bh * DH * NPB + ch * 512;
    bool doq = (wc == 0), dok = (wr == 0);
    f32x4 acc[2][2] = {};
    float sq[2] = {0.f, 0.f}, sk[2] = {0.f, 0.f};
    for (int n = 0; n < 512; n += 32) {
        short8 a[2], b[2];
#pragma unroll
        for (int i = 0; i < 2; i++)
            a[i] = *(const short8*)&qrow[(size_t)(wr * 32 + i * 16 + l15) * NPB + n + k8 * 8];
#pragma unroll
        for (int j = 0; j < 2; j++)
            b[j] = *(const short8*)&krow[(size_t)(wc * 32 + j * 16 + l15) * NPB + n + k8 * 8];
        if (doq) {
#pragma unroll
            for (int i = 0; i < 2; i++)
#pragma unroll
                for (int u = 0; u < 8; u++) {
                    float f = bf2f((ushort)a[i][u]); sq[i] += f * f;
                }
        }
        if (dok) {
#pragma unroll
            for (int j = 0; j < 2; j++)
#pragma unroll
                for (int u = 0; u < 8; u++) {
                    float f = bf2f((ushort)b[j][u]); sk[j] += f * f;
                }
        }
#pragma unroll
        for (int i = 0; i < 2; i++)
#pragma unroll
            for (int j = 0; j < 2; j++)
                acc[i][j] = __builtin_amdgcn_mfma_f32_16x16x32_bf16(a[i], b[j], acc[i][j], 0, 0, 0);
    }
    float* S2o = S2 + ((size_t)ch * 64 + bh) * 192;
    if (doq) {
#pragma unroll
        for (int i = 0; i < 2; i++) {
            float v = sq[i];
            v += __shfl_xor(v, 16); v += __shfl_xor(v, 32);
            if (lane < 16) S2o[wr * 32 + i * 16 + l15] = v;
        }
    }
    if (dok) {
#pragma unroll
        for (int j = 0; j < 2; j++) {
            float v = sk[j];
            v += __shfl_xor(v, 16); v += __shfl_xor(v, 32);
            if (lane < 16) S2o[96 + wc * 32 + j * 16 + l15] = v;
        }
    }
    float* So = S + ((size_t)ch * 64 + bh) * (DH * DH);
#pragma unroll
    for (int i = 0; i < 2; i++)
#pragma unroll
        for (int j = 0; j < 2; j++) {
            int e = wc * 32 + j * 16 + l15;
#pragma unroll
            for (int qq = 0; qq < 4; qq++) {
                int d = wr * 32 + i * 16 + k8 * 4 + qq;
                So[d * DH + e] = acc[i][j][qq];
            }
        }
}

// ---------------- attn softmax: reduce chunks + sumsq, write attn^T --------
// grid (64, 3), 192 threads: 32 rows x 6 col-groups of 16
__global__ __launch_bounds__(192) void attn_soft_kernel(
    const float* __restrict__ S, const float* __restrict__ S2,
    const float* __restrict__ temp, ushort* __restrict__ attnT) {
    int bh = blockIdx.x, ds0 = blockIdx.y * 32;
    int tid = threadIdx.x, r = tid & 31, p = tid >> 5;
    int d = ds0 + r;
    __shared__ float rkv[96];
    if (tid < 96) {
        float sum = 0.f;
#pragma unroll 1
        for (int ch = 0; ch < 8; ch++)
            sum += S2[((size_t)ch * 64 + bh) * 192 + 96 + tid];
        rkv[tid] = 1.0f / fmaxf(sqrtf(sum), 1e-12f);
    }
    float sqd = 0.f;
#pragma unroll 1
    for (int ch = 0; ch < 8; ch++)
        sqd += S2[((size_t)ch * 64 + bh) * 192 + d];
    float rqd = 1.0f / fmaxf(sqrtf(sqd), 1e-12f);
    float4 v[4] = {};
#pragma unroll 1
    for (int ch = 0; ch < 8; ch++) {
        const float* So = S + (((size_t)ch * 64 + bh) * DH + d) * DH + p * 16;
#pragma unroll
        for (int u = 0; u < 4; u++) {
            float4 w = *(const float4*)&So[u * 4];
            v[u].x += w.x; v[u].y += w.y; v[u].z += w.z; v[u].w += w.w;
        }
    }
    __syncthreads();   // rkv ready
    float sd = rqd * temp[bh & (HEADS - 1)];
#pragma unroll
    for (int u = 0; u < 4; u++) {
        int e0 = p * 16 + u * 4;
        v[u].x *= sd * rkv[e0]; v[u].y *= sd * rkv[e0 + 1];
        v[u].z *= sd * rkv[e0 + 2]; v[u].w *= sd * rkv[e0 + 3];
    }
    __shared__ float red[32][8], red2[32][8];
    float lm = -3.4e38f;
#pragma unroll
    for (int u = 0; u < 4; u++)
        lm = fmaxf(lm, fmaxf(fmaxf(v[u].x, v[u].y), fmaxf(v[u].z, v[u].w)));
    red[r][p] = lm;
    __syncthreads();
    float m = red[r][0];
#pragma unroll
    for (int u = 1; u < 6; u++) m = fmaxf(m, red[r][u]);
    float s = 0.f;
#pragma unroll
    for (int u = 0; u < 4; u++) {
        v[u].x = __expf(v[u].x - m); v[u].y = __expf(v[u].y - m);
        v[u].z = __expf(v[u].z - m); v[u].w = __expf(v[u].w - m);
        s += v[u].x + v[u].y + v[u].z + v[u].w;
    }
    red2[r][p] = s;
    __syncthreads();
    float tot = red2[r][0];
#pragma unroll
    for (int u = 1; u < 6; u++) tot += red2[r][u];
    float inv = 1.0f / tot;
    // transposed store: attnT[bh][e][d]
    ushort* ao = attnT + (size_t)bh * (DH * DH) + d;
#pragma unroll
    for (int u = 0; u < 4; u++) {
        int e0 = p * 16 + u * 4;
        ao[(e0 + 0) * DH] = f2bf(v[u].x * inv);
        ao[(e0 + 1) * DH] = f2bf(v[u].y * inv);
        ao[(e0 + 2) * DH] = f2bf(v[u].z * inv);
        ao[(e0 + 3) * DH] = f2bf(v[u].w * inv);
    }
}

// ---------------- W2 prep: W2[b][o][h*96+e] = sum_d pw[o][h*96+d]*attn[d][e]
// grid (64, 3): (bh, o-tile of 256); 4 waves, each 64 o-rows x 96 e
__global__ __launch_bounds__(256) void w2prep_kernel(
    const ushort* __restrict__ pwb, const ushort* __restrict__ attnT,
    ushort* __restrict__ W2) {
    int bh = blockIdx.x, o0 = blockIdx.y * 256;
    int b_ = bh >> 3, h = bh & 7;
    int tid = threadIdx.x, wid = tid >> 6, lane = tid & 63;
    int k8 = lane >> 4, l15 = lane & 15;
    const ushort* at = attnT + (size_t)bh * (DH * DH);
    f32x4 acc[4][6] = {};
#pragma unroll
    for (int kk = 0; kk < DH; kk += 32) {
        short8 af[4], bf[6];
#pragma unroll
        for (int m = 0; m < 4; m++)
            af[m] = *(const short8*)&pwb[(size_t)(o0 + wid * 64 + m * 16 + l15) * DIMC
                                         + h * DH + kk + k8 * 8];
#pragma unroll
        for (int n = 0; n < 6; n++)
            bf[n] = *(const short8*)&at[(n * 16 + l15) * DH + kk + k8 * 8];
#pragma unroll
        for (int m = 0; m < 4; m++)
#pragma unroll
            for (int n = 0; n < 6; n++)
                acc[m][n] = __builtin_amdgcn_mfma_f32_16x16x32_bf16(af[m], bf[n], acc[m][n], 0, 0, 0);
    }
    ushort* wo = W2 + (size_t)b_ * DIMC * DIMC + (size_t)h * DH;
#pragma unroll
    for (int m = 0; m < 4; m++) {
        int orow = o0 + wid * 64 + m * 16 + k8 * 4;
#pragma unroll
        for (int n = 0; n < 6; n++) {
            int e = n * 16 + l15;
#pragma unroll
            for (int qq = 0; qq < 4; qq++)
                wo[(size_t)(orow + qq) * DIMC + e] = f2bf(acc[m][n][qq]);
        }
    }
}

// ---------------- vproj: out = g1*(v·W2[b]^T + pb) + x  (256x256 BK=32) ----
__global__ __launch_bounds__(512) void vproj_kernel(
    const ushort* __restrict__ vb, const ushort* __restrict__ W2,
    const float* __restrict__ pb, const float* __restrict__ g1,
    const float* __restrict__ x, float* __restrict__ out) {
    __shared__ __align__(16) char lds[65536];
    int orig = blockIdx.x;                   // 0..383
    int wg = (orig & 7) * 48 + (orig >> 3);
    int b_ = wg / 48, rem = wg % 48, mt = rem / 3, ntl = rem % 3;
    int tok0 = b_ * NPB + mt * 256, o0 = ntl * 256;
    f32x4 acc[8][4] = {};
    gemm256_core((const char*)(vb + (size_t)tok0 * DIMC),
                 (const char*)(W2 + (size_t)b_ * DIMC * DIMC + (size_t)o0 * DIMC),
                 lds, acc);

    int tid = threadIdx.x, lane = tid & 63, wid = tid >> 6;
    int wr = wid >> 2, wc = wid & 3;
    int k8 = lane >> 4, l15 = lane & 15;
#pragma unroll
    for (int m8 = 0; m8 < 8; m8++) {
        int r0 = tok0 + wr * 128 + m8 * 16 + k8 * 4;
#pragma unroll
        for (int n = 0; n < 4; n++) {
            int o = o0 + wc * 64 + n * 16 + l15;
            float pbo = pb[o], g1o = g1[o];
            f32x4 a = acc[m8][n];
#pragma unroll
            for (int qq = 0; qq < 4; qq++) {
                size_t idx = (size_t)(r0 + qq) * DIMC + o;
                out[idx] = g1o * (a[qq] + pbo) + x[idx];
            }
        }
    }
}

extern "C" void kernel_launch(void* const* d_in, const int* in_sizes, int n_in,
                              void* d_out, int out_size, void* d_ws, size_t ws_size,
                              hipStream_t stream) {
    const float* x     = (const float*)d_in[0];
    const float* qkvw  = (const float*)d_in[1];
    const float* projw = (const float*)d_in[2];
    const float* projb = (const float*)d_in[3];
    const float* lng   = (const float*)d_in[4];
    const float* lnb   = (const float*)d_in[5];
    const float* temp  = (const float*)d_in[6];
    const float* g1    = (const float*)d_in[7];
    float* out = (float*)d_out;

    char* w = (char*)d_ws;
    ushort* qb    = (ushort*)(w + 0);            // 50,331,648  [B,H,dh,N]
    ushort* kb    = (ushort*)(w + 50331648);     // 50,331,648
    ushort* vb    = (ushort*)(w + 100663296);    // 50,331,648  [T, C] token-major
    ushort* qwb   = (ushort*)(w + 150994944);    // 3,538,944  (dead after qkv)
    ushort* pwb   = (ushort*)(w + 154533888);    // 1,179,648
    float*  S2    = (float*)(w + 155713536);     // 393,216 sumsq partials
    ushort* attnT = qwb;                         // 1,179,648 (aliases dead qwb)
    ushort* W2    = qb;                          // 9,437,184 (aliases dead qb)
    ushort* xb    = (ushort*)d_out;              // LN output (dead before vproj)
    float*  S     = (float*)((char*)d_out + 50331648);  // 18.9 MB attn partials

    hipLaunchKernelGGL(prep_w_kernel, dim3(1728), dim3(256), 0, stream,
                       qkvw, projw, qwb, pwb);
    hipLaunchKernelGGL(ln_cvt_kernel, dim3(8192), dim3(256), 0, stream,
                       x, lng, lnb, xb);
    hipLaunchKernelGGL(gemm_qkv_kernel, dim3(1152), dim3(512), 0, stream,
                       xb, qwb, qb, kb, vb);
    hipLaunchKernelGGL(attn_qk_kernel, dim3(64, 8), dim3(576), 0, stream,
                       qb, kb, S, S2);
    hipLaunchKernelGGL(attn_soft_kernel, dim3(64, 3), dim3(192), 0, stream,
                       S, S2, temp, attnT);
    hipLaunchKernelGGL(w2prep_kernel, dim3(64, 3), dim3(256), 0, stream,
                       pwb, attnT, W2);
    hipLaunchKernelGGL(vproj_kernel, dim3(384), dim3(512), 0, stream,
                       vb, W2, projb, g1, x, out);
}

// Round 9
// 256.626 us; speedup vs baseline: 1.9880x; 1.2547x over previous
//
#include <hip/hip_runtime.h>
#include <hip/hip_bf16.h>
#include <stdint.h>

typedef __attribute__((ext_vector_type(8))) short short8;
typedef __attribute__((ext_vector_type(4))) float f32x4;
typedef __attribute__((ext_vector_type(4))) unsigned short us4;

#define DIMC 768
#define NTOK 32768
#define NPB 4096
#define HEADS 8
#define DH 96

__device__ __forceinline__ ushort f2bf(float f) {
    union { float f; uint32_t u; } c; c.f = f;
    uint32_t u = c.u;
    u += 0x7fffu + ((u >> 16) & 1u);
    return (ushort)(u >> 16);
}
__device__ __forceinline__ float bf2f(ushort h) {
    union { uint32_t u; float f; } c; c.u = ((uint32_t)h) << 16;
    return c.f;
}

__device__ __forceinline__ void gload_lds16(const void* g, void* l) {
    __builtin_amdgcn_global_load_lds(
        (const __attribute__((address_space(1))) void*)g,
        (__attribute__((address_space(3))) void*)l, 16, 0, 0);
}

// =====================================================================
// 256x256-tile BK=32 GEMM core, 8 waves, m201-style schedule:
// 4 phases per iteration (2 K-tiles), 2 barriers/phase, lgkm(0) BETWEEN
// barrier and MFMA, counted vmcnt only at Ph3/Ph4.
// LDS 64 KiB: A[2][256][32] + B[2][256][32] bf16 (2 blocks/CU),
// st_16x32 swizzle, linear gload_lds dest + pre-swizzled global source.
// Iteration i: tiles t0=2i (buf0), t1=2i+1 (buf1).
//   Ph1: read bf(buf0)+af0-3(buf0); stage A(2i+1)->buf1;       [A-buf1 free]
//   Ph2: read af4-7(buf0);          stage B(2i+2)->buf0;       [B-buf0 free]
//   Ph3: read bf(buf1)+af0-3(buf1); stage A(2i+2)->buf0; vm(4) [A-buf0 free]
//   Ph4: read af4-7(buf1);          stage B(2i+3)->buf1; vm(2) [B-buf1 free]
// vm(4) drains B(t1),A(t1) (consumed Ph3/4); vm(2) drains B/A(2i+2)
// (consumed next Ph1).  Each stage region's readers drained one barrier
// earlier (lgkm(0) precedes the intervening barrier in the reader phase).
// =====================================================================
__device__ __forceinline__ void gemm256_core(
    const char* aglob, const char* bglob, char* lds, f32x4 (&acc)[8][4]) {
    const int tid = threadIdx.x;
    const int lane = tid & 63, wid = tid >> 6;
    const int wr = wid >> 2, wc = wid & 3;
    const int k8 = lane >> 4, l15 = lane & 15;

    const int L0 = tid * 16, L1 = (512 + tid) * 16;
    const int S0 = L0 ^ (((L0 >> 9) & 1) << 5);
    const int S1 = L1 ^ (((L1 >> 9) & 1) << 5);
    const int sr0 = S0 >> 6, sc0 = S0 & 63;
    const int sr1 = S1 >> 6, sc1 = S1 & 63;

    int aoff[8], boff[4];
#pragma unroll
    for (int m = 0; m < 8; m++) {
        int row = wr * 128 + m * 16 + l15;
        int o = row * 64 + k8 * 16;
        aoff[m] = o ^ (((o >> 9) & 1) << 5);
    }
#pragma unroll
    for (int n = 0; n < 4; n++) {
        int row = wc * 64 + n * 16 + l15;
        int o = row * 64 + k8 * 16;
        boff[n] = o ^ (((o >> 9) & 1) << 5);
    }

#define STG_A(kt, c) do {                                     \
        const char* ak_ = aglob + (size_t)(kt) * 64;          \
        char* al_ = lds + (c) * 16384;                        \
        gload_lds16(ak_ + sr0 * 1536 + sc0, al_ + L0);        \
        gload_lds16(ak_ + sr1 * 1536 + sc1, al_ + L1);        \
    } while (0)
#define STG_B(kt, c) do {                                     \
        const char* bk_ = bglob + (size_t)(kt) * 64;          \
        char* bl_ = lds + 32768 + (c) * 16384;                \
        gload_lds16(bk_ + sr0 * 1536 + sc0, bl_ + L0);        \
        gload_lds16(bk_ + sr1 * 1536 + sc1, bl_ + L1);        \
    } while (0)
#define MFMA16(mb)                                                                 \
    __builtin_amdgcn_s_setprio(1);                                                 \
    _Pragma("unroll")                                                              \
    for (int m_ = 0; m_ < 4; m_++)                                                 \
        _Pragma("unroll")                                                          \
        for (int n_ = 0; n_ < 4; n_++)                                             \
            acc[(mb) + m_][n_] = __builtin_amdgcn_mfma_f32_16x16x32_bf16(          \
                af[m_], bf[n_], acc[(mb) + m_][n_], 0, 0, 0);                      \
    __builtin_amdgcn_s_setprio(0);
#define BAR  asm volatile("s_barrier" ::: "memory")
#define LGKM0 do { asm volatile("s_waitcnt lgkmcnt(0)" ::: "memory"); \
                   __builtin_amdgcn_sched_barrier(0); } while (0)

    // prologue: B(0),A(0) drained; B(1) in flight
    STG_B(0, 0); STG_A(0, 0); STG_B(1, 1);
    asm volatile("s_waitcnt vmcnt(2)" ::: "memory");
    BAR;

    const char* a0 = lds;
    const char* a1 = lds + 16384;
    const char* b0 = lds + 32768;
    const char* b1 = lds + 49152;

#pragma unroll
    for (int i = 0; i < 6; ++i) {
        short8 af[4], bf[4];
        // ---- Ph1: tile 2i (buf0), m0-3 ----
#pragma unroll
        for (int n = 0; n < 4; n++) bf[n] = *(const short8*)(b0 + boff[n]);
#pragma unroll
        for (int m = 0; m < 4; m++) af[m] = *(const short8*)(a0 + aoff[m]);
        STG_A(2 * i + 1, 1);
        BAR;
        LGKM0;
        MFMA16(0)
        BAR;
        // ---- Ph2: tile 2i (buf0), m4-7 ----
#pragma unroll
        for (int m = 0; m < 4; m++) af[m] = *(const short8*)(a0 + aoff[4 + m]);
        if (2 * i + 2 < 12) STG_B(2 * i + 2, 0);
        BAR;
        LGKM0;
        MFMA16(4)
        BAR;
        // ---- Ph3: tile 2i+1 (buf1), m0-3 ----
#pragma unroll
        for (int n = 0; n < 4; n++) bf[n] = *(const short8*)(b1 + boff[n]);
#pragma unroll
        for (int m = 0; m < 4; m++) af[m] = *(const short8*)(a1 + aoff[m]);
        if (2 * i + 2 < 12) STG_A(2 * i + 2, 0);
        if (i < 5) asm volatile("s_waitcnt vmcnt(4)" ::: "memory");
        else       asm volatile("s_waitcnt vmcnt(0)" ::: "memory");
        BAR;
        LGKM0;
        MFMA16(0)
        BAR;
        // ---- Ph4: tile 2i+1 (buf1), m4-7 ----
#pragma unroll
        for (int m = 0; m < 4; m++) af[m] = *(const short8*)(a1 + aoff[4 + m]);
        if (2 * i + 3 < 12) STG_B(2 * i + 3, 1);
        if (i < 5) asm volatile("s_waitcnt vmcnt(2)" ::: "memory");
        else       asm volatile("s_waitcnt vmcnt(0)" ::: "memory");
        BAR;
        LGKM0;
        MFMA16(4)
        BAR;
    }
#undef STG_A
#undef STG_B
#undef MFMA16
#undef BAR
#undef LGKM0
}

// ---------------- weight prep: bf16 casts, vectorized ----------------
__global__ __launch_bounds__(256) void prep_w_kernel(
    const float* __restrict__ qw, const float* __restrict__ pw,
    ushort* __restrict__ qwb, ushort* __restrict__ pwb) {
    int i4 = (blockIdx.x * 256 + threadIdx.x) * 4;
    if (i4 < 3 * DIMC * DIMC) {
        float4 w = *(const float4*)&qw[i4];
        us4 o;
        o[0] = f2bf(w.x); o[1] = f2bf(w.y); o[2] = f2bf(w.z); o[3] = f2bf(w.w);
        *(us4*)&qwb[i4] = o;
    }
    if (i4 < DIMC * DIMC) {
        float4 w = *(const float4*)&pw[i4];
        us4 o;
        o[0] = f2bf(w.x); o[1] = f2bf(w.y); o[2] = f2bf(w.z); o[3] = f2bf(w.w);
        *(us4*)&pwb[i4] = o;
    }
}

// ---------------- LayerNorm + cast: xb = bf16(ln(x)*g + b) ----------------
__global__ __launch_bounds__(256) void ln_cvt_kernel(
    const float* __restrict__ x, const float* __restrict__ g,
    const float* __restrict__ b, ushort* __restrict__ xb) {
    int t = blockIdx.x * 4 + (threadIdx.x >> 6);
    int lane = threadIdx.x & 63;
    const float* xr = x + (size_t)t * DIMC;
    float4 v[3];
    float s = 0.f, s2 = 0.f;
#pragma unroll
    for (int u = 0; u < 3; u++) {
        v[u] = *(const float4*)&xr[u * 256 + lane * 4];
        s  += v[u].x + v[u].y + v[u].z + v[u].w;
        s2 += v[u].x * v[u].x + v[u].y * v[u].y + v[u].z * v[u].z + v[u].w * v[u].w;
    }
#pragma unroll
    for (int off = 32; off > 0; off >>= 1) {
        s  += __shfl_down(s, off);
        s2 += __shfl_down(s2, off);
    }
    s = __shfl(s, 0);
    s2 = __shfl(s2, 0);
    float mean = s * (1.0f / DIMC);
    float rstd = rsqrtf(s2 * (1.0f / DIMC) - mean * mean + 1e-5f);
    ushort* xo = xb + (size_t)t * DIMC;
#pragma unroll
    for (int u = 0; u < 3; u++) {
        float4 gv = *(const float4*)&g[u * 256 + lane * 4];
        float4 bv = *(const float4*)&b[u * 256 + lane * 4];
        us4 o;
        o[0] = f2bf((v[u].x - mean) * rstd * gv.x + bv.x);
        o[1] = f2bf((v[u].y - mean) * rstd * gv.y + bv.y);
        o[2] = f2bf((v[u].z - mean) * rstd * gv.z + bv.z);
        o[3] = f2bf((v[u].w - mean) * rstd * gv.w + bv.w);
        *(us4*)&xo[u * 256 + lane * 4] = o;
    }
}

// ---------------- QKV GEMM: 256x256 m201-schedule pipelined ----------------
__global__ __launch_bounds__(512) void gemm_qkv_kernel(
    const ushort* __restrict__ xb, const ushort* __restrict__ wb,
    ushort* __restrict__ qb, ushort* __restrict__ kb, ushort* __restrict__ vb) {
    __shared__ __align__(16) char lds[65536];
    int orig = blockIdx.x;                   // 0..1151
    int wg = (orig & 7) * 144 + (orig >> 3);
    int nt = wg % 9, mt = wg / 9;
    int m0 = mt * 256, n0 = nt * 256;
    f32x4 acc[8][4] = {};
    gemm256_core((const char*)(xb + (size_t)m0 * DIMC),
                 (const char*)(wb + (size_t)n0 * DIMC), lds, acc);

    int tid = threadIdx.x, lane = tid & 63, wid = tid >> 6;
    int wr = wid >> 2, wc = wid & 3;
    int k8 = lane >> 4, l15 = lane & 15;
    int seg = n0 / DIMC;                     // 0=q, 1=k, 2=v (no straddle)
#pragma unroll
    for (int m8 = 0; m8 < 8; m8++) {
        int r0 = m0 + wr * 128 + m8 * 16 + k8 * 4;
        int b_ = r0 >> 12, nn = r0 & (NPB - 1);
#pragma unroll
        for (int n = 0; n < 4; n++) {
            int o = n0 + wc * 64 + n * 16 + l15;
            f32x4 a = acc[m8][n];
            if (seg == 2) {
                int oL = o - 2 * DIMC;
#pragma unroll
                for (int qq = 0; qq < 4; qq++)
                    vb[(size_t)(r0 + qq) * DIMC + oL] = f2bf(a[qq]);
            } else {
                int oL = o - seg * DIMC;
                int h = oL / DH, d = oL - h * DH;
                us4 pk;
#pragma unroll
                for (int qq = 0; qq < 4; qq++) pk[qq] = f2bf(a[qq]);
                *(us4*)((seg ? kb : qb) +
                        ((size_t)(b_ * HEADS + h) * DH + d) * NPB + nn) = pk;
            }
        }
    }
}

// ---------------- attn partial: S[ch][bh][96][96] + q/k sumsq partials -----
// grid (64, 8), 9 waves; q sumsq by waves wc==0, k sumsq by wr==0
__global__ __launch_bounds__(576) void attn_qk_kernel(
    const ushort* __restrict__ qb, const ushort* __restrict__ kb,
    float* __restrict__ S, float* __restrict__ S2) {
    int bh = blockIdx.x, ch = blockIdx.y;
    int tid = threadIdx.x, wid = tid >> 6, lane = tid & 63;
    int wr = wid / 3, wc = wid - wr * 3;
    int k8 = lane >> 4, l15 = lane & 15;
    const ushort* qrow = qb + (size_t)bh * DH * NPB + ch * 512;
    const ushort* krow = kb + (size_t)bh * DH * NPB + ch * 512;
    bool doq = (wc == 0), dok = (wr == 0);
    f32x4 acc[2][2] = {};
    float sq[2] = {0.f, 0.f}, sk[2] = {0.f, 0.f};
    for (int n = 0; n < 512; n += 32) {
        short8 a[2], b[2];
#pragma unroll
        for (int i = 0; i < 2; i++)
            a[i] = *(const short8*)&qrow[(size_t)(wr * 32 + i * 16 + l15) * NPB + n + k8 * 8];
#pragma unroll
        for (int j = 0; j < 2; j++)
            b[j] = *(const short8*)&krow[(size_t)(wc * 32 + j * 16 + l15) * NPB + n + k8 * 8];
        if (doq) {
#pragma unroll
            for (int i = 0; i < 2; i++)
#pragma unroll
                for (int u = 0; u < 8; u++) {
                    float f = bf2f((ushort)a[i][u]); sq[i] += f * f;
                }
        }
        if (dok) {
#pragma unroll
            for (int j = 0; j < 2; j++)
#pragma unroll
                for (int u = 0; u < 8; u++) {
                    float f = bf2f((ushort)b[j][u]); sk[j] += f * f;
                }
        }
#pragma unroll
        for (int i = 0; i < 2; i++)
#pragma unroll
            for (int j = 0; j < 2; j++)
                acc[i][j] = __builtin_amdgcn_mfma_f32_16x16x32_bf16(a[i], b[j], acc[i][j], 0, 0, 0);
    }
    float* S2o = S2 + ((size_t)ch * 64 + bh) * 192;
    if (doq) {
#pragma unroll
        for (int i = 0; i < 2; i++) {
            float v = sq[i];
            v += __shfl_xor(v, 16); v += __shfl_xor(v, 32);
            if (lane < 16) S2o[wr * 32 + i * 16 + l15] = v;
        }
    }
    if (dok) {
#pragma unroll
        for (int j = 0; j < 2; j++) {
            float v = sk[j];
            v += __shfl_xor(v, 16); v += __shfl_xor(v, 32);
            if (lane < 16) S2o[96 + wc * 32 + j * 16 + l15] = v;
        }
    }
    float* So = S + ((size_t)ch * 64 + bh) * (DH * DH);
#pragma unroll
    for (int i = 0; i < 2; i++)
#pragma unroll
        for (int j = 0; j < 2; j++) {
            int e = wc * 32 + j * 16 + l15;
#pragma unroll
            for (int qq = 0; qq < 4; qq++) {
                int d = wr * 32 + i * 16 + k8 * 4 + qq;
                So[d * DH + e] = acc[i][j][qq];
            }
        }
}

// ---------------- attn softmax: reduce chunks + sumsq, write attn^T --------
// grid (64, 3), 192 threads: 32 rows x 6 col-groups of 16
__global__ __launch_bounds__(192) void attn_soft_kernel(
    const float* __restrict__ S, const float* __restrict__ S2,
    const float* __restrict__ temp, ushort* __restrict__ attnT) {
    int bh = blockIdx.x, ds0 = blockIdx.y * 32;
    int tid = threadIdx.x, r = tid & 31, p = tid >> 5;
    int d = ds0 + r;
    __shared__ float rkv[96];
    if (tid < 96) {
        float sum = 0.f;
#pragma unroll 1
        for (int ch = 0; ch < 8; ch++)
            sum += S2[((size_t)ch * 64 + bh) * 192 + 96 + tid];
        rkv[tid] = 1.0f / fmaxf(sqrtf(sum), 1e-12f);
    }
    float sqd = 0.f;
#pragma unroll 1
    for (int ch = 0; ch < 8; ch++)
        sqd += S2[((size_t)ch * 64 + bh) * 192 + d];
    float rqd = 1.0f / fmaxf(sqrtf(sqd), 1e-12f);
    float4 v[4] = {};
#pragma unroll 1
    for (int ch = 0; ch < 8; ch++) {
        const float* So = S + (((size_t)ch * 64 + bh) * DH + d) * DH + p * 16;
#pragma unroll
        for (int u = 0; u < 4; u++) {
            float4 w = *(const float4*)&So[u * 4];
            v[u].x += w.x; v[u].y += w.y; v[u].z += w.z; v[u].w += w.w;
        }
    }
    __syncthreads();   // rkv ready
    float sd = rqd * temp[bh & (HEADS - 1)];
#pragma unroll
    for (int u = 0; u < 4; u++) {
        int e0 = p * 16 + u * 4;
        v[u].x *= sd * rkv[e0]; v[u].y *= sd * rkv[e0 + 1];
        v[u].z *= sd * rkv[e0 + 2]; v[u].w *= sd * rkv[e0 + 3];
    }
    __shared__ float red[32][8], red2[32][8];
    float lm = -3.4e38f;
#pragma unroll
    for (int u = 0; u < 4; u++)
        lm = fmaxf(lm, fmaxf(fmaxf(v[u].x, v[u].y), fmaxf(v[u].z, v[u].w)));
    red[r][p] = lm;
    __syncthreads();
    float m = red[r][0];
#pragma unroll
    for (int u = 1; u < 6; u++) m = fmaxf(m, red[r][u]);
    float s = 0.f;
#pragma unroll
    for (int u = 0; u < 4; u++) {
        v[u].x = __expf(v[u].x - m); v[u].y = __expf(v[u].y - m);
        v[u].z = __expf(v[u].z - m); v[u].w = __expf(v[u].w - m);
        s += v[u].x + v[u].y + v[u].z + v[u].w;
    }
    red2[r][p] = s;
    __syncthreads();
    float tot = red2[r][0];
#pragma unroll
    for (int u = 1; u < 6; u++) tot += red2[r][u];
    float inv = 1.0f / tot;
    // transposed store: attnT[bh][e][d]
    ushort* ao = attnT + (size_t)bh * (DH * DH) + d;
#pragma unroll
    for (int u = 0; u < 4; u++) {
        int e0 = p * 16 + u * 4;
        ao[(e0 + 0) * DH] = f2bf(v[u].x * inv);
        ao[(e0 + 1) * DH] = f2bf(v[u].y * inv);
        ao[(e0 + 2) * DH] = f2bf(v[u].z * inv);
        ao[(e0 + 3) * DH] = f2bf(v[u].w * inv);
    }
}

// ---------------- W2 prep: W2[b][o][h*96+e] = sum_d pw[o][h*96+d]*attn[d][e]
// grid (64, 3): (bh, o-tile of 256); 4 waves, each 64 o-rows x 96 e
__global__ __launch_bounds__(256) void w2prep_kernel(
    const ushort* __restrict__ pwb, const ushort* __restrict__ attnT,
    ushort* __restrict__ W2) {
    int bh = blockIdx.x, o0 = blockIdx.y * 256;
    int b_ = bh >> 3, h = bh & 7;
    int tid = threadIdx.x, wid = tid >> 6, lane = tid & 63;
    int k8 = lane >> 4, l15 = lane & 15;
    const ushort* at = attnT + (size_t)bh * (DH * DH);
    f32x4 acc[4][6] = {};
#pragma unroll
    for (int kk = 0; kk < DH; kk += 32) {
        short8 af[4], bf[6];
#pragma unroll
        for (int m = 0; m < 4; m++)
            af[m] = *(const short8*)&pwb[(size_t)(o0 + wid * 64 + m * 16 + l15) * DIMC
                                         + h * DH + kk + k8 * 8];
#pragma unroll
        for (int n = 0; n < 6; n++)
            bf[n] = *(const short8*)&at[(n * 16 + l15) * DH + kk + k8 * 8];
#pragma unroll
        for (int m = 0; m < 4; m++)
#pragma unroll
            for (int n = 0; n < 6; n++)
                acc[m][n] = __builtin_amdgcn_mfma_f32_16x16x32_bf16(af[m], bf[n], acc[m][n], 0, 0, 0);
    }
    ushort* wo = W2 + (size_t)b_ * DIMC * DIMC + (size_t)h * DH;
#pragma unroll
    for (int m = 0; m < 4; m++) {
        int orow = o0 + wid * 64 + m * 16 + k8 * 4;
#pragma unroll
        for (int n = 0; n < 6; n++) {
            int e = n * 16 + l15;
#pragma unroll
            for (int qq = 0; qq < 4; qq++)
                wo[(size_t)(orow + qq) * DIMC + e] = f2bf(acc[m][n][qq]);
        }
    }
}

// ---------------- vproj: out = g1*(v·W2[b]^T + pb) + x  (256x256 BK=32) ----
__global__ __launch_bounds__(512) void vproj_kernel(
    const ushort* __restrict__ vb, const ushort* __restrict__ W2,
    const float* __restrict__ pb, const float* __restrict__ g1,
    const float* __restrict__ x, float* __restrict__ out) {
    __shared__ __align__(16) char lds[65536];
    int orig = blockIdx.x;                   // 0..383
    int wg = (orig & 7) * 48 + (orig >> 3);
    int b_ = wg / 48, rem = wg % 48, mt = rem / 3, ntl = rem % 3;
    int tok0 = b_ * NPB + mt * 256, o0 = ntl * 256;
    f32x4 acc[8][4] = {};
    gemm256_core((const char*)(vb + (size_t)tok0 * DIMC),
                 (const char*)(W2 + (size_t)b_ * DIMC * DIMC + (size_t)o0 * DIMC),
                 lds, acc);

    int tid = threadIdx.x, lane = tid & 63, wid = tid >> 6;
    int wr = wid >> 2, wc = wid & 3;
    int k8 = lane >> 4, l15 = lane & 15;
#pragma unroll
    for (int m8 = 0; m8 < 8; m8++) {
        int r0 = tok0 + wr * 128 + m8 * 16 + k8 * 4;
#pragma unroll
        for (int n = 0; n < 4; n++) {
            int o = o0 + wc * 64 + n * 16 + l15;
            float pbo = pb[o], g1o = g1[o];
            f32x4 a = acc[m8][n];
#pragma unroll
            for (int qq = 0; qq < 4; qq++) {
                size_t idx = (size_t)(r0 + qq) * DIMC + o;
                out[idx] = g1o * (a[qq] + pbo) + x[idx];
            }
        }
    }
}

extern "C" void kernel_launch(void* const* d_in, const int* in_sizes, int n_in,
                              void* d_out, int out_size, void* d_ws, size_t ws_size,
                              hipStream_t stream) {
    const float* x     = (const float*)d_in[0];
    const float* qkvw  = (const float*)d_in[1];
    const float* projw = (const float*)d_in[2];
    const float* projb = (const float*)d_in[3];
    const float* lng   = (const float*)d_in[4];
    const float* lnb   = (const float*)d_in[5];
    const float* temp  = (const float*)d_in[6];
    const float* g1    = (const float*)d_in[7];
    float* out = (float*)d_out;

    char* w = (char*)d_ws;
    ushort* qb    = (ushort*)(w + 0);            // 50,331,648  [B,H,dh,N]
    ushort* kb    = (ushort*)(w + 50331648);     // 50,331,648
    ushort* vb    = (ushort*)(w + 100663296);    // 50,331,648  [T, C] token-major
    ushort* qwb   = (ushort*)(w + 150994944);    // 3,538,944  (dead after qkv)
    ushort* pwb   = (ushort*)(w + 154533888);    // 1,179,648
    float*  S2    = (float*)(w + 155713536);     // 393,216 sumsq partials
    ushort* attnT = qwb;                         // 1,179,648 (aliases dead qwb)
    ushort* W2    = qb;                          // 9,437,184 (aliases dead qb)
    ushort* xb    = (ushort*)d_out;              // LN output (dead before vproj)
    float*  S     = (float*)((char*)d_out + 50331648);  // 18.9 MB attn partials

    hipLaunchKernelGGL(prep_w_kernel, dim3(1728), dim3(256), 0, stream,
                       qkvw, projw, qwb, pwb);
    hipLaunchKernelGGL(ln_cvt_kernel, dim3(8192), dim3(256), 0, stream,
                       x, lng, lnb, xb);
    hipLaunchKernelGGL(gemm_qkv_kernel, dim3(1152), dim3(512), 0, stream,
                       xb, qwb, qb, kb, vb);
    hipLaunchKernelGGL(attn_qk_kernel, dim3(64, 8), dim3(576), 0, stream,
                       qb, kb, S, S2);
    hipLaunchKernelGGL(attn_soft_kernel, dim3(64, 3), dim3(192), 0, stream,
                       S, S2, temp, attnT);
    hipLaunchKernelGGL(w2prep_kernel, dim3(64, 3), dim3(256), 0, stream,
                       pwb, attnT, W2);
    hipLaunchKernelGGL(vproj_kernel, dim3(384), dim3(512), 0, stream,
                       vb, W2, projb, g1, x, out);
}

// Round 10
// 253.535 us; speedup vs baseline: 2.0122x; 1.0122x over previous
//
#include <hip/hip_runtime.h>
#include <hip/hip_bf16.h>
#include <stdint.h>

typedef __attribute__((ext_vector_type(8))) short short8;
typedef __attribute__((ext_vector_type(4))) float f32x4;
typedef __attribute__((ext_vector_type(4))) unsigned short us4;

#define DIMC 768
#define NTOK 32768
#define NPB 4096
#define HEADS 8
#define DH 96

__device__ __forceinline__ ushort f2bf(float f) {
    union { float f; uint32_t u; } c; c.f = f;
    uint32_t u = c.u;
    u += 0x7fffu + ((u >> 16) & 1u);
    return (ushort)(u >> 16);
}
__device__ __forceinline__ float bf2f(ushort h) {
    union { uint32_t u; float f; } c; c.u = ((uint32_t)h) << 16;
    return c.f;
}

__device__ __forceinline__ void gload_lds16(const void* g, void* l) {
    __builtin_amdgcn_global_load_lds(
        (const __attribute__((address_space(1))) void*)g,
        (__attribute__((address_space(3))) void*)l, 16, 0, 0);
}

// =====================================================================
// 256x256-tile BK=32 GEMM core, 8 waves, m201-style 4-phase/2-K-tile
// schedule with RACE-FIXED counted vmcnt placement:
//   counted vmcnt sits at the END of the phase PRECEDING consumption,
//   before that phase's closing barrier (so after the barrier, the staged
//   buffer is globally valid for the next phase's ds_reads).
// LDS 64 KiB: A[2][256][32] + B[2][256][32] bf16 (2 blocks/CU),
// st_16x32 swizzle, linear gload_lds dest + pre-swizzled global source.
// Iteration i (tiles 2i->buf0, 2i+1->buf1):
//  Ph1: read b0,a0[0-3]; STG A(2i+1)->buf1; BAR; lgkm0; MFMA; BAR
//  Ph2: read a0[4-7];    STG B(2i+2)->buf0; BAR; lgkm0; MFMA; vm(2); BAR
//       [vm(2): B(2i+1),A(2i+1) landed; B(2i+2) in flight -> Ph3 reads safe]
//  Ph3: read b1,a1[0-3]; STG A(2i+2)->buf0; BAR; lgkm0; MFMA; BAR
//  Ph4: read a1[4-7];    STG B(2i+3)->buf1; BAR; lgkm0; MFMA; vm(2); BAR
//       [vm(2): B(2i+2),A(2i+2) landed; B(2i+3) in flight -> next Ph1 safe]
// Outstanding-load ledger (2 loads per STG): end-Ph2 = 6 -> vm(2); end-Ph4
// = 6 -> vm(2). Tail i=5: Ph2 vm(0) (A11 must land for Ph3), Ph4 no wait.
// Region overwrite safety: every stage target's readers drained by their
// phase's lgkm0 before the closing barrier one barrier ahead of the stage.
// =====================================================================
__device__ __forceinline__ void gemm256_core(
    const char* aglob, const char* bglob, char* lds, f32x4 (&acc)[8][4]) {
    const int tid = threadIdx.x;
    const int lane = tid & 63, wid = tid >> 6;
    const int wr = wid >> 2, wc = wid & 3;
    const int k8 = lane >> 4, l15 = lane & 15;

    const int L0 = tid * 16, L1 = (512 + tid) * 16;
    const int S0 = L0 ^ (((L0 >> 9) & 1) << 5);
    const int S1 = L1 ^ (((L1 >> 9) & 1) << 5);
    const int sr0 = S0 >> 6, sc0 = S0 & 63;
    const int sr1 = S1 >> 6, sc1 = S1 & 63;

    int aoff[8], boff[4];
#pragma unroll
    for (int m = 0; m < 8; m++) {
        int row = wr * 128 + m * 16 + l15;
        int o = row * 64 + k8 * 16;
        aoff[m] = o ^ (((o >> 9) & 1) << 5);
    }
#pragma unroll
    for (int n = 0; n < 4; n++) {
        int row = wc * 64 + n * 16 + l15;
        int o = row * 64 + k8 * 16;
        boff[n] = o ^ (((o >> 9) & 1) << 5);
    }

#define STG_A(kt, c) do {                                     \
        const char* ak_ = aglob + (size_t)(kt) * 64;          \
        char* al_ = lds + (c) * 16384;                        \
        gload_lds16(ak_ + sr0 * 1536 + sc0, al_ + L0);        \
        gload_lds16(ak_ + sr1 * 1536 + sc1, al_ + L1);        \
    } while (0)
#define STG_B(kt, c) do {                                     \
        const char* bk_ = bglob + (size_t)(kt) * 64;          \
        char* bl_ = lds + 32768 + (c) * 16384;                \
        gload_lds16(bk_ + sr0 * 1536 + sc0, bl_ + L0);        \
        gload_lds16(bk_ + sr1 * 1536 + sc1, bl_ + L1);        \
    } while (0)
#define MFMA16(mb)                                                                 \
    __builtin_amdgcn_s_setprio(1);                                                 \
    _Pragma("unroll")                                                              \
    for (int m_ = 0; m_ < 4; m_++)                                                 \
        _Pragma("unroll")                                                          \
        for (int n_ = 0; n_ < 4; n_++)                                             \
            acc[(mb) + m_][n_] = __builtin_amdgcn_mfma_f32_16x16x32_bf16(          \
                af[m_], bf[n_], acc[(mb) + m_][n_], 0, 0, 0);                      \
    __builtin_amdgcn_s_setprio(0);
#define BAR  asm volatile("s_barrier" ::: "memory")
#define LGKM0 do { asm volatile("s_waitcnt lgkmcnt(0)" ::: "memory"); \
                   __builtin_amdgcn_sched_barrier(0); } while (0)

    // prologue: B(0),A(0) drained; B(1) in flight
    STG_B(0, 0); STG_A(0, 0); STG_B(1, 1);
    asm volatile("s_waitcnt vmcnt(2)" ::: "memory");
    BAR;

    const char* a0 = lds;
    const char* a1 = lds + 16384;
    const char* b0 = lds + 32768;
    const char* b1 = lds + 49152;

#pragma unroll
    for (int i = 0; i < 6; ++i) {
        short8 af[4], bf[4];
        // ---- Ph1: tile 2i (buf0), m0-3 ----
#pragma unroll
        for (int n = 0; n < 4; n++) bf[n] = *(const short8*)(b0 + boff[n]);
#pragma unroll
        for (int m = 0; m < 4; m++) af[m] = *(const short8*)(a0 + aoff[m]);
        STG_A(2 * i + 1, 1);
        BAR;
        LGKM0;
        MFMA16(0)
        BAR;
        // ---- Ph2: tile 2i (buf0), m4-7 ----
#pragma unroll
        for (int m = 0; m < 4; m++) af[m] = *(const short8*)(a0 + aoff[4 + m]);
        if (2 * i + 2 < 12) STG_B(2 * i + 2, 0);
        BAR;
        LGKM0;
        MFMA16(4)
        if (i < 5) asm volatile("s_waitcnt vmcnt(2)" ::: "memory");
        else       asm volatile("s_waitcnt vmcnt(0)" ::: "memory");
        BAR;       // staged B(2i+1)/A(2i+1) now valid block-wide
        // ---- Ph3: tile 2i+1 (buf1), m0-3 ----
#pragma unroll
        for (int n = 0; n < 4; n++) bf[n] = *(const short8*)(b1 + boff[n]);
#pragma unroll
        for (int m = 0; m < 4; m++) af[m] = *(const short8*)(a1 + aoff[m]);
        if (2 * i + 2 < 12) STG_A(2 * i + 2, 0);
        BAR;
        LGKM0;
        MFMA16(0)
        BAR;
        // ---- Ph4: tile 2i+1 (buf1), m4-7 ----
#pragma unroll
        for (int m = 0; m < 4; m++) af[m] = *(const short8*)(a1 + aoff[4 + m]);
        if (2 * i + 3 < 12) STG_B(2 * i + 3, 1);
        BAR;
        LGKM0;
        MFMA16(4)
        if (i < 5) {
            asm volatile("s_waitcnt vmcnt(2)" ::: "memory");
            BAR;   // staged B(2i+2)/A(2i+2) now valid block-wide
        }
    }
#undef STG_A
#undef STG_B
#undef MFMA16
#undef BAR
#undef LGKM0
}

// ---------------- fused prep: weight bf16 casts + LayerNorm cast -----------
// blocks [0,1728): weights; blocks [1728,9920): LN tokens (4 per block)
__global__ __launch_bounds__(256) void prep_fused_kernel(
    const float* __restrict__ qw, const float* __restrict__ pw,
    ushort* __restrict__ qwb, ushort* __restrict__ pwb,
    const float* __restrict__ x, const float* __restrict__ g,
    const float* __restrict__ b, ushort* __restrict__ xb) {
    int bid = blockIdx.x;
    if (bid < 1728) {
        int i4 = (bid * 256 + threadIdx.x) * 4;
        if (i4 < 3 * DIMC * DIMC) {
            float4 w = *(const float4*)&qw[i4];
            us4 o;
            o[0] = f2bf(w.x); o[1] = f2bf(w.y); o[2] = f2bf(w.z); o[3] = f2bf(w.w);
            *(us4*)&qwb[i4] = o;
        }
        if (i4 < DIMC * DIMC) {
            float4 w = *(const float4*)&pw[i4];
            us4 o;
            o[0] = f2bf(w.x); o[1] = f2bf(w.y); o[2] = f2bf(w.z); o[3] = f2bf(w.w);
            *(us4*)&pwb[i4] = o;
        }
        return;
    }
    int t = (bid - 1728) * 4 + (threadIdx.x >> 6);
    int lane = threadIdx.x & 63;
    const float* xr = x + (size_t)t * DIMC;
    float4 v[3];
    float s = 0.f, s2 = 0.f;
#pragma unroll
    for (int u = 0; u < 3; u++) {
        v[u] = *(const float4*)&xr[u * 256 + lane * 4];
        s  += v[u].x + v[u].y + v[u].z + v[u].w;
        s2 += v[u].x * v[u].x + v[u].y * v[u].y + v[u].z * v[u].z + v[u].w * v[u].w;
    }
#pragma unroll
    for (int off = 32; off > 0; off >>= 1) {
        s  += __shfl_down(s, off);
        s2 += __shfl_down(s2, off);
    }
    s = __shfl(s, 0);
    s2 = __shfl(s2, 0);
    float mean = s * (1.0f / DIMC);
    float rstd = rsqrtf(s2 * (1.0f / DIMC) - mean * mean + 1e-5f);
    ushort* xo = xb + (size_t)t * DIMC;
#pragma unroll
    for (int u = 0; u < 3; u++) {
        float4 gv = *(const float4*)&g[u * 256 + lane * 4];
        float4 bv = *(const float4*)&b[u * 256 + lane * 4];
        us4 o;
        o[0] = f2bf((v[u].x - mean) * rstd * gv.x + bv.x);
        o[1] = f2bf((v[u].y - mean) * rstd * gv.y + bv.y);
        o[2] = f2bf((v[u].z - mean) * rstd * gv.z + bv.z);
        o[3] = f2bf((v[u].w - mean) * rstd * gv.w + bv.w);
        *(us4*)&xo[u * 256 + lane * 4] = o;
    }
}

// ---------------- QKV GEMM: 256x256 m201-schedule pipelined ----------------
__global__ __launch_bounds__(512) void gemm_qkv_kernel(
    const ushort* __restrict__ xb, const ushort* __restrict__ wb,
    ushort* __restrict__ qb, ushort* __restrict__ kb, ushort* __restrict__ vb) {
    __shared__ __align__(16) char lds[65536];
    int orig = blockIdx.x;                   // 0..1151
    int wg = (orig & 7) * 144 + (orig >> 3);
    int nt = wg % 9, mt = wg / 9;
    int m0 = mt * 256, n0 = nt * 256;
    f32x4 acc[8][4] = {};
    gemm256_core((const char*)(xb + (size_t)m0 * DIMC),
                 (const char*)(wb + (size_t)n0 * DIMC), lds, acc);

    int tid = threadIdx.x, lane = tid & 63, wid = tid >> 6;
    int wr = wid >> 2, wc = wid & 3;
    int k8 = lane >> 4, l15 = lane & 15;
    int seg = n0 / DIMC;                     // 0=q, 1=k, 2=v (no straddle)
#pragma unroll
    for (int m8 = 0; m8 < 8; m8++) {
        int r0 = m0 + wr * 128 + m8 * 16 + k8 * 4;
        int b_ = r0 >> 12, nn = r0 & (NPB - 1);
#pragma unroll
        for (int n = 0; n < 4; n++) {
            int o = n0 + wc * 64 + n * 16 + l15;
            f32x4 a = acc[m8][n];
            if (seg == 2) {
                int oL = o - 2 * DIMC;
#pragma unroll
                for (int qq = 0; qq < 4; qq++)
                    vb[(size_t)(r0 + qq) * DIMC + oL] = f2bf(a[qq]);
            } else {
                int oL = o - seg * DIMC;
                int h = oL / DH, d = oL - h * DH;
                us4 pk;
#pragma unroll
                for (int qq = 0; qq < 4; qq++) pk[qq] = f2bf(a[qq]);
                *(us4*)((seg ? kb : qb) +
                        ((size_t)(b_ * HEADS + h) * DH + d) * NPB + nn) = pk;
            }
        }
    }
}

// ---------------- attn partial: S[ch][bh][96][96] + q/k sumsq partials -----
// grid (64, 8), 9 waves; q sumsq by waves wc==0, k sumsq by wr==0
__global__ __launch_bounds__(576) void attn_qk_kernel(
    const ushort* __restrict__ qb, const ushort* __restrict__ kb,
    float* __restrict__ S, float* __restrict__ S2) {
    int bh = blockIdx.x, ch = blockIdx.y;
    int tid = threadIdx.x, wid = tid >> 6, lane = tid & 63;
    int wr = wid / 3, wc = wid - wr * 3;
    int k8 = lane >> 4, l15 = lane & 15;
    const ushort* qrow = qb + (size_t)bh * DH * NPB + ch * 512;
    const ushort* krow = kb + (size_t)bh * DH * NPB + ch * 512;
    bool doq = (wc == 0), dok = (wr == 0);
    f32x4 acc[2][2] = {};
    float sq[2] = {0.f, 0.f}, sk[2] = {0.f, 0.f};
    for (int n = 0; n < 512; n += 32) {
        short8 a[2], b[2];
#pragma unroll
        for (int i = 0; i < 2; i++)
            a[i] = *(const short8*)&qrow[(size_t)(wr * 32 + i * 16 + l15) * NPB + n + k8 * 8];
#pragma unroll
        for (int j = 0; j < 2; j++)
            b[j] = *(const short8*)&krow[(size_t)(wc * 32 + j * 16 + l15) * NPB + n + k8 * 8];
        if (doq) {
#pragma unroll
            for (int i = 0; i < 2; i++)
#pragma unroll
                for (int u = 0; u < 8; u++) {
                    float f = bf2f((ushort)a[i][u]); sq[i] += f * f;
                }
        }
        if (dok) {
#pragma unroll
            for (int j = 0; j < 2; j++)
#pragma unroll
                for (int u = 0; u < 8; u++) {
                    float f = bf2f((ushort)b[j][u]); sk[j] += f * f;
                }
        }
#pragma unroll
        for (int i = 0; i < 2; i++)
#pragma unroll
            for (int j = 0; j < 2; j++)
                acc[i][j] = __builtin_amdgcn_mfma_f32_16x16x32_bf16(a[i], b[j], acc[i][j], 0, 0, 0);
    }
    float* S2o = S2 + ((size_t)ch * 64 + bh) * 192;
    if (doq) {
#pragma unroll
        for (int i = 0; i < 2; i++) {
            float v = sq[i];
            v += __shfl_xor(v, 16); v += __shfl_xor(v, 32);
            if (lane < 16) S2o[wr * 32 + i * 16 + l15] = v;
        }
    }
    if (dok) {
#pragma unroll
        for (int j = 0; j < 2; j++) {
            float v = sk[j];
            v += __shfl_xor(v, 16); v += __shfl_xor(v, 32);
            if (lane < 16) S2o[96 + wc * 32 + j * 16 + l15] = v;
        }
    }
    float* So = S + ((size_t)ch * 64 + bh) * (DH * DH);
#pragma unroll
    for (int i = 0; i < 2; i++)
#pragma unroll
        for (int j = 0; j < 2; j++) {
            int e = wc * 32 + j * 16 + l15;
#pragma unroll
            for (int qq = 0; qq < 4; qq++) {
                int d = wr * 32 + i * 16 + k8 * 4 + qq;
                So[d * DH + e] = acc[i][j][qq];
            }
        }
}

// ---------------- attn softmax: reduce chunks + sumsq, write attn^T --------
// grid (64, 3), 192 threads: 32 rows x 6 col-groups of 16
__global__ __launch_bounds__(192) void attn_soft_kernel(
    const float* __restrict__ S, const float* __restrict__ S2,
    const float* __restrict__ temp, ushort* __restrict__ attnT) {
    int bh = blockIdx.x, ds0 = blockIdx.y * 32;
    int tid = threadIdx.x, r = tid & 31, p = tid >> 5;
    int d = ds0 + r;
    __shared__ float rkv[96];
    if (tid < 96) {
        float sum = 0.f;
#pragma unroll 1
        for (int ch = 0; ch < 8; ch++)
            sum += S2[((size_t)ch * 64 + bh) * 192 + 96 + tid];
        rkv[tid] = 1.0f / fmaxf(sqrtf(sum), 1e-12f);
    }
    float sqd = 0.f;
#pragma unroll 1
    for (int ch = 0; ch < 8; ch++)
        sqd += S2[((size_t)ch * 64 + bh) * 192 + d];
    float rqd = 1.0f / fmaxf(sqrtf(sqd), 1e-12f);
    float4 v[4] = {};
#pragma unroll 1
    for (int ch = 0; ch < 8; ch++) {
        const float* So = S + (((size_t)ch * 64 + bh) * DH + d) * DH + p * 16;
#pragma unroll
        for (int u = 0; u < 4; u++) {
            float4 w = *(const float4*)&So[u * 4];
            v[u].x += w.x; v[u].y += w.y; v[u].z += w.z; v[u].w += w.w;
        }
    }
    __syncthreads();   // rkv ready
    float sd = rqd * temp[bh & (HEADS - 1)];
#pragma unroll
    for (int u = 0; u < 4; u++) {
        int e0 = p * 16 + u * 4;
        v[u].x *= sd * rkv[e0]; v[u].y *= sd * rkv[e0 + 1];
        v[u].z *= sd * rkv[e0 + 2]; v[u].w *= sd * rkv[e0 + 3];
    }
    __shared__ float red[32][8], red2[32][8];
    float lm = -3.4e38f;
#pragma unroll
    for (int u = 0; u < 4; u++)
        lm = fmaxf(lm, fmaxf(fmaxf(v[u].x, v[u].y), fmaxf(v[u].z, v[u].w)));
    red[r][p] = lm;
    __syncthreads();
    float m = red[r][0];
#pragma unroll
    for (int u = 1; u < 6; u++) m = fmaxf(m, red[r][u]);
    float s = 0.f;
#pragma unroll
    for (int u = 0; u < 4; u++) {
        v[u].x = __expf(v[u].x - m); v[u].y = __expf(v[u].y - m);
        v[u].z = __expf(v[u].z - m); v[u].w = __expf(v[u].w - m);
        s += v[u].x + v[u].y + v[u].z + v[u].w;
    }
    red2[r][p] = s;
    __syncthreads();
    float tot = red2[r][0];
#pragma unroll
    for (int u = 1; u < 6; u++) tot += red2[r][u];
    float inv = 1.0f / tot;
    // transposed store: attnT[bh][e][d]
    ushort* ao = attnT + (size_t)bh * (DH * DH) + d;
#pragma unroll
    for (int u = 0; u < 4; u++) {
        int e0 = p * 16 + u * 4;
        ao[(e0 + 0) * DH] = f2bf(v[u].x * inv);
        ao[(e0 + 1) * DH] = f2bf(v[u].y * inv);
        ao[(e0 + 2) * DH] = f2bf(v[u].z * inv);
        ao[(e0 + 3) * DH] = f2bf(v[u].w * inv);
    }
}

// ---------------- W2 prep: W2[b][o][h*96+e] = sum_d pw[o][h*96+d]*attn[d][e]
// grid (64, 3): (bh, o-tile of 256); 4 waves, each 64 o-rows x 96 e
__global__ __launch_bounds__(256) void w2prep_kernel(
    const ushort* __restrict__ pwb, const ushort* __restrict__ attnT,
    ushort* __restrict__ W2) {
    int bh = blockIdx.x, o0 = blockIdx.y * 256;
    int b_ = bh >> 3, h = bh & 7;
    int tid = threadIdx.x, wid = tid >> 6, lane = tid & 63;
    int k8 = lane >> 4, l15 = lane & 15;
    const ushort* at = attnT + (size_t)bh * (DH * DH);
    f32x4 acc[4][6] = {};
#pragma unroll
    for (int kk = 0; kk < DH; kk += 32) {
        short8 af[4], bf[6];
#pragma unroll
        for (int m = 0; m < 4; m++)
            af[m] = *(const short8*)&pwb[(size_t)(o0 + wid * 64 + m * 16 + l15) * DIMC
                                         + h * DH + kk + k8 * 8];
#pragma unroll
        for (int n = 0; n < 6; n++)
            bf[n] = *(const short8*)&at[(n * 16 + l15) * DH + kk + k8 * 8];
#pragma unroll
        for (int m = 0; m < 4; m++)
#pragma unroll
            for (int n = 0; n < 6; n++)
                acc[m][n] = __builtin_amdgcn_mfma_f32_16x16x32_bf16(af[m], bf[n], acc[m][n], 0, 0, 0);
    }
    ushort* wo = W2 + (size_t)b_ * DIMC * DIMC + (size_t)h * DH;
#pragma unroll
    for (int m = 0; m < 4; m++) {
        int orow = o0 + wid * 64 + m * 16 + k8 * 4;
#pragma unroll
        for (int n = 0; n < 6; n++) {
            int e = n * 16 + l15;
#pragma unroll
            for (int qq = 0; qq < 4; qq++)
                wo[(size_t)(orow + qq) * DIMC + e] = f2bf(acc[m][n][qq]);
        }
    }
}

// ---------------- vproj: out = g1*(v·W2[b]^T + pb) + x  (256x256 BK=32) ----
__global__ __launch_bounds__(512) void vproj_kernel(
    const ushort* __restrict__ vb, const ushort* __restrict__ W2,
    const float* __restrict__ pb, const float* __restrict__ g1,
    const float* __restrict__ x, float* __restrict__ out) {
    __shared__ __align__(16) char lds[65536];
    int orig = blockIdx.x;                   // 0..383
    int wg = (orig & 7) * 48 + (orig >> 3);
    int b_ = wg / 48, rem = wg % 48, mt = rem / 3, ntl = rem % 3;
    int tok0 = b_ * NPB + mt * 256, o0 = ntl * 256;
    f32x4 acc[8][4] = {};
    gemm256_core((const char*)(vb + (size_t)tok0 * DIMC),
                 (const char*)(W2 + (size_t)b_ * DIMC * DIMC + (size_t)o0 * DIMC),
                 lds, acc);

    int tid = threadIdx.x, lane = tid & 63, wid = tid >> 6;
    int wr = wid >> 2, wc = wid & 3;
    int k8 = lane >> 4, l15 = lane & 15;
#pragma unroll
    for (int m8 = 0; m8 < 8; m8++) {
        int r0 = tok0 + wr * 128 + m8 * 16 + k8 * 4;
#pragma unroll
        for (int n = 0; n < 4; n++) {
            int o = o0 + wc * 64 + n * 16 + l15;
            float pbo = pb[o], g1o = g1[o];
            f32x4 a = acc[m8][n];
#pragma unroll
            for (int qq = 0; qq < 4; qq++) {
                size_t idx = (size_t)(r0 + qq) * DIMC + o;
                out[idx] = g1o * (a[qq] + pbo) + x[idx];
            }
        }
    }
}

extern "C" void kernel_launch(void* const* d_in, const int* in_sizes, int n_in,
                              void* d_out, int out_size, void* d_ws, size_t ws_size,
                              hipStream_t stream) {
    const float* x     = (const float*)d_in[0];
    const float* qkvw  = (const float*)d_in[1];
    const float* projw = (const float*)d_in[2];
    const float* projb = (const float*)d_in[3];
    const float* lng   = (const float*)d_in[4];
    const float* lnb   = (const float*)d_in[5];
    const float* temp  = (const float*)d_in[6];
    const float* g1    = (const float*)d_in[7];
    float* out = (float*)d_out;

    char* w = (char*)d_ws;
    ushort* qb    = (ushort*)(w + 0);            // 50,331,648  [B,H,dh,N]
    ushort* kb    = (ushort*)(w + 50331648);     // 50,331,648
    ushort* vb    = (ushort*)(w + 100663296);    // 50,331,648  [T, C] token-major
    ushort* qwb   = (ushort*)(w + 150994944);    // 3,538,944  (dead after qkv)
    ushort* pwb   = (ushort*)(w + 154533888);    // 1,179,648
    float*  S2    = (float*)(w + 155713536);     // 393,216 sumsq partials
    ushort* attnT = qwb;                         // 1,179,648 (aliases dead qwb)
    ushort* W2    = qb;                          // 9,437,184 (aliases dead qb)
    ushort* xb    = (ushort*)d_out;              // LN output (dead before vproj)
    float*  S     = (float*)((char*)d_out + 50331648);  // 18.9 MB attn partials

    hipLaunchKernelGGL(prep_fused_kernel, dim3(9920), dim3(256), 0, stream,
                       qkvw, projw, qwb, pwb, x, lng, lnb, xb);
    hipLaunchKernelGGL(gemm_qkv_kernel, dim3(1152), dim3(512), 0, stream,
                       xb, qwb, qb, kb, vb);
    hipLaunchKernelGGL(attn_qk_kernel, dim3(64, 8), dim3(576), 0, stream,
                       qb, kb, S, S2);
    hipLaunchKernelGGL(attn_soft_kernel, dim3(64, 3), dim3(192), 0, stream,
                       S, S2, temp, attnT);
    hipLaunchKernelGGL(w2prep_kernel, dim3(64, 3), dim3(256), 0, stream,
                       pwb, attnT, W2);
    hipLaunchKernelGGL(vproj_kernel, dim3(384), dim3(512), 0, stream,
                       vb, W2, projb, g1, x, out);
}

// Round 11
// 253.480 us; speedup vs baseline: 2.0127x; 1.0002x over previous
//
#include <hip/hip_runtime.h>
#include <hip/hip_bf16.h>
#include <stdint.h>

typedef __attribute__((ext_vector_type(8))) short short8;
typedef __attribute__((ext_vector_type(4))) float f32x4;
typedef __attribute__((ext_vector_type(4))) unsigned short us4;

#define DIMC 768
#define NTOK 32768
#define NPB 4096
#define HEADS 8
#define DH 96

__device__ __forceinline__ ushort f2bf(float f) {
    union { float f; uint32_t u; } c; c.f = f;
    uint32_t u = c.u;
    u += 0x7fffu + ((u >> 16) & 1u);
    return (ushort)(u >> 16);
}
__device__ __forceinline__ float bf2f(ushort h) {
    union { uint32_t u; float f; } c; c.u = ((uint32_t)h) << 16;
    return c.f;
}

__device__ __forceinline__ void gload_lds16(const void* g, void* l) {
    __builtin_amdgcn_global_load_lds(
        (const __attribute__((address_space(1))) void*)g,
        (__attribute__((address_space(3))) void*)l, 16, 0, 0);
}

// =====================================================================
// 256x256-tile BK=32 GEMM core (R10-measured: qkv 102us, 0 bank conflicts).
// m201-style 4-phase/2-K-tile schedule, race-fixed counted vmcnt.
// =====================================================================
__device__ __forceinline__ void gemm256_core(
    const char* aglob, const char* bglob, char* lds, f32x4 (&acc)[8][4]) {
    const int tid = threadIdx.x;
    const int lane = tid & 63, wid = tid >> 6;
    const int wr = wid >> 2, wc = wid & 3;
    const int k8 = lane >> 4, l15 = lane & 15;

    const int L0 = tid * 16, L1 = (512 + tid) * 16;
    const int S0 = L0 ^ (((L0 >> 9) & 1) << 5);
    const int S1 = L1 ^ (((L1 >> 9) & 1) << 5);
    const int sr0 = S0 >> 6, sc0 = S0 & 63;
    const int sr1 = S1 >> 6, sc1 = S1 & 63;

    int aoff[8], boff[4];
#pragma unroll
    for (int m = 0; m < 8; m++) {
        int row = wr * 128 + m * 16 + l15;
        int o = row * 64 + k8 * 16;
        aoff[m] = o ^ (((o >> 9) & 1) << 5);
    }
#pragma unroll
    for (int n = 0; n < 4; n++) {
        int row = wc * 64 + n * 16 + l15;
        int o = row * 64 + k8 * 16;
        boff[n] = o ^ (((o >> 9) & 1) << 5);
    }

#define STG_A(kt, c) do {                                     \
        const char* ak_ = aglob + (size_t)(kt) * 64;          \
        char* al_ = lds + (c) * 16384;                        \
        gload_lds16(ak_ + sr0 * 1536 + sc0, al_ + L0);        \
        gload_lds16(ak_ + sr1 * 1536 + sc1, al_ + L1);        \
    } while (0)
#define STG_B(kt, c) do {                                     \
        const char* bk_ = bglob + (size_t)(kt) * 64;          \
        char* bl_ = lds + 32768 + (c) * 16384;                \
        gload_lds16(bk_ + sr0 * 1536 + sc0, bl_ + L0);        \
        gload_lds16(bk_ + sr1 * 1536 + sc1, bl_ + L1);        \
    } while (0)
#define MFMA16(mb)                                                                 \
    __builtin_amdgcn_s_setprio(1);                                                 \
    _Pragma("unroll")                                                              \
    for (int m_ = 0; m_ < 4; m_++)                                                 \
        _Pragma("unroll")                                                          \
        for (int n_ = 0; n_ < 4; n_++)                                             \
            acc[(mb) + m_][n_] = __builtin_amdgcn_mfma_f32_16x16x32_bf16(          \
                af[m_], bf[n_], acc[(mb) + m_][n_], 0, 0, 0);                      \
    __builtin_amdgcn_s_setprio(0);
#define BAR  asm volatile("s_barrier" ::: "memory")
#define LGKM0 do { asm volatile("s_waitcnt lgkmcnt(0)" ::: "memory"); \
                   __builtin_amdgcn_sched_barrier(0); } while (0)

    STG_B(0, 0); STG_A(0, 0); STG_B(1, 1);
    asm volatile("s_waitcnt vmcnt(2)" ::: "memory");
    BAR;

    const char* a0 = lds;
    const char* a1 = lds + 16384;
    const char* b0 = lds + 32768;
    const char* b1 = lds + 49152;

#pragma unroll
    for (int i = 0; i < 6; ++i) {
        short8 af[4], bf[4];
        // ---- Ph1: tile 2i (buf0), m0-3 ----
#pragma unroll
        for (int n = 0; n < 4; n++) bf[n] = *(const short8*)(b0 + boff[n]);
#pragma unroll
        for (int m = 0; m < 4; m++) af[m] = *(const short8*)(a0 + aoff[m]);
        STG_A(2 * i + 1, 1);
        BAR;
        LGKM0;
        MFMA16(0)
        BAR;
        // ---- Ph2: tile 2i (buf0), m4-7 ----
#pragma unroll
        for (int m = 0; m < 4; m++) af[m] = *(const short8*)(a0 + aoff[4 + m]);
        if (2 * i + 2 < 12) STG_B(2 * i + 2, 0);
        BAR;
        LGKM0;
        MFMA16(4)
        if (i < 5) asm volatile("s_waitcnt vmcnt(2)" ::: "memory");
        else       asm volatile("s_waitcnt vmcnt(0)" ::: "memory");
        BAR;       // staged B(2i+1)/A(2i+1) now valid block-wide
        // ---- Ph3: tile 2i+1 (buf1), m0-3 ----
#pragma unroll
        for (int n = 0; n < 4; n++) bf[n] = *(const short8*)(b1 + boff[n]);
#pragma unroll
        for (int m = 0; m < 4; m++) af[m] = *(const short8*)(a1 + aoff[m]);
        if (2 * i + 2 < 12) STG_A(2 * i + 2, 0);
        BAR;
        LGKM0;
        MFMA16(0)
        BAR;
        // ---- Ph4: tile 2i+1 (buf1), m4-7 ----
#pragma unroll
        for (int m = 0; m < 4; m++) af[m] = *(const short8*)(a1 + aoff[4 + m]);
        if (2 * i + 3 < 12) STG_B(2 * i + 3, 1);
        BAR;
        LGKM0;
        MFMA16(4)
        if (i < 5) {
            asm volatile("s_waitcnt vmcnt(2)" ::: "memory");
            BAR;   // staged B(2i+2)/A(2i+2) now valid block-wide
        }
    }
#undef STG_A
#undef STG_B
#undef MFMA16
#undef BAR
#undef LGKM0
}

// ---------------- fused prep: weight bf16 casts + LayerNorm cast -----------
__global__ __launch_bounds__(256) void prep_fused_kernel(
    const float* __restrict__ qw, const float* __restrict__ pw,
    ushort* __restrict__ qwb, ushort* __restrict__ pwb,
    const float* __restrict__ x, const float* __restrict__ g,
    const float* __restrict__ b, ushort* __restrict__ xb) {
    int bid = blockIdx.x;
    if (bid < 1728) {
        int i4 = (bid * 256 + threadIdx.x) * 4;
        if (i4 < 3 * DIMC * DIMC) {
            float4 w = *(const float4*)&qw[i4];
            us4 o;
            o[0] = f2bf(w.x); o[1] = f2bf(w.y); o[2] = f2bf(w.z); o[3] = f2bf(w.w);
            *(us4*)&qwb[i4] = o;
        }
        if (i4 < DIMC * DIMC) {
            float4 w = *(const float4*)&pw[i4];
            us4 o;
            o[0] = f2bf(w.x); o[1] = f2bf(w.y); o[2] = f2bf(w.z); o[3] = f2bf(w.w);
            *(us4*)&pwb[i4] = o;
        }
        return;
    }
    int t = (bid - 1728) * 4 + (threadIdx.x >> 6);
    int lane = threadIdx.x & 63;
    const float* xr = x + (size_t)t * DIMC;
    float4 v[3];
    float s = 0.f, s2 = 0.f;
#pragma unroll
    for (int u = 0; u < 3; u++) {
        v[u] = *(const float4*)&xr[u * 256 + lane * 4];
        s  += v[u].x + v[u].y + v[u].z + v[u].w;
        s2 += v[u].x * v[u].x + v[u].y * v[u].y + v[u].z * v[u].z + v[u].w * v[u].w;
    }
#pragma unroll
    for (int off = 32; off > 0; off >>= 1) {
        s  += __shfl_down(s, off);
        s2 += __shfl_down(s2, off);
    }
    s = __shfl(s, 0);
    s2 = __shfl(s2, 0);
    float mean = s * (1.0f / DIMC);
    float rstd = rsqrtf(s2 * (1.0f / DIMC) - mean * mean + 1e-5f);
    ushort* xo = xb + (size_t)t * DIMC;
#pragma unroll
    for (int u = 0; u < 3; u++) {
        float4 gv = *(const float4*)&g[u * 256 + lane * 4];
        float4 bv = *(const float4*)&b[u * 256 + lane * 4];
        us4 o;
        o[0] = f2bf((v[u].x - mean) * rstd * gv.x + bv.x);
        o[1] = f2bf((v[u].y - mean) * rstd * gv.y + bv.y);
        o[2] = f2bf((v[u].z - mean) * rstd * gv.z + bv.z);
        o[3] = f2bf((v[u].w - mean) * rstd * gv.w + bv.w);
        *(us4*)&xo[u * 256 + lane * 4] = o;
    }
}

// ---------------- QKV GEMM: 256x256 m201-schedule pipelined ----------------
__global__ __launch_bounds__(512) void gemm_qkv_kernel(
    const ushort* __restrict__ xb, const ushort* __restrict__ wb,
    ushort* __restrict__ qb, ushort* __restrict__ kb, ushort* __restrict__ vb) {
    __shared__ __align__(16) char lds[65536];
    int orig = blockIdx.x;                   // 0..1151
    int wg = (orig & 7) * 144 + (orig >> 3);
    int nt = wg % 9, mt = wg / 9;
    int m0 = mt * 256, n0 = nt * 256;
    f32x4 acc[8][4] = {};
    gemm256_core((const char*)(xb + (size_t)m0 * DIMC),
                 (const char*)(wb + (size_t)n0 * DIMC), lds, acc);

    int tid = threadIdx.x, lane = tid & 63, wid = tid >> 6;
    int wr = wid >> 2, wc = wid & 3;
    int k8 = lane >> 4, l15 = lane & 15;
    int seg = n0 / DIMC;                     // 0=q, 1=k, 2=v (no straddle)
#pragma unroll
    for (int m8 = 0; m8 < 8; m8++) {
        int r0 = m0 + wr * 128 + m8 * 16 + k8 * 4;
        int b_ = r0 >> 12, nn = r0 & (NPB - 1);
#pragma unroll
        for (int n = 0; n < 4; n++) {
            int o = n0 + wc * 64 + n * 16 + l15;
            f32x4 a = acc[m8][n];
            if (seg == 2) {
                int oL = o - 2 * DIMC;
#pragma unroll
                for (int qq = 0; qq < 4; qq++)
                    vb[(size_t)(r0 + qq) * DIMC + oL] = f2bf(a[qq]);
            } else {
                int oL = o - seg * DIMC;
                int h = oL / DH, d = oL - h * DH;
                us4 pk;
#pragma unroll
                for (int qq = 0; qq < 4; qq++) pk[qq] = f2bf(a[qq]);
                *(us4*)((seg ? kb : qb) +
                        ((size_t)(b_ * HEADS + h) * DH + d) * NPB + nn) = pk;
            }
        }
    }
}

// ---------------- attn partial: S[ch][bh][96][96] (bf16) + sumsq partials --
// grid (64, 8), 9 waves; q sumsq by waves wc==0, k sumsq by wr==0
__global__ __launch_bounds__(576) void attn_qk_kernel(
    const ushort* __restrict__ qb, const ushort* __restrict__ kb,
    ushort* __restrict__ S, float* __restrict__ S2) {
    int bh = blockIdx.x, ch = blockIdx.y;
    int tid = threadIdx.x, wid = tid >> 6, lane = tid & 63;
    int wr = wid / 3, wc = wid - wr * 3;
    int k8 = lane >> 4, l15 = lane & 15;
    const ushort* qrow = qb + (size_t)bh * DH * NPB + ch * 512;
    const ushort* krow = kb + (size_t)bh * DH * NPB + ch * 512;
    bool doq = (wc == 0), dok = (wr == 0);
    f32x4 acc[2][2] = {};
    float sq[2] = {0.f, 0.f}, sk[2] = {0.f, 0.f};
    for (int n = 0; n < 512; n += 32) {
        short8 a[2], b[2];
#pragma unroll
        for (int i = 0; i < 2; i++)
            a[i] = *(const short8*)&qrow[(size_t)(wr * 32 + i * 16 + l15) * NPB + n + k8 * 8];
#pragma unroll
        for (int j = 0; j < 2; j++)
            b[j] = *(const short8*)&krow[(size_t)(wc * 32 + j * 16 + l15) * NPB + n + k8 * 8];
        if (doq) {
#pragma unroll
            for (int i = 0; i < 2; i++)
#pragma unroll
                for (int u = 0; u < 8; u++) {
                    float f = bf2f((ushort)a[i][u]); sq[i] += f * f;
                }
        }
        if (dok) {
#pragma unroll
            for (int j = 0; j < 2; j++)
#pragma unroll
                for (int u = 0; u < 8; u++) {
                    float f = bf2f((ushort)b[j][u]); sk[j] += f * f;
                }
        }
#pragma unroll
        for (int i = 0; i < 2; i++)
#pragma unroll
            for (int j = 0; j < 2; j++)
                acc[i][j] = __builtin_amdgcn_mfma_f32_16x16x32_bf16(a[i], b[j], acc[i][j], 0, 0, 0);
    }
    float* S2o = S2 + ((size_t)ch * 64 + bh) * 192;
    if (doq) {
#pragma unroll
        for (int i = 0; i < 2; i++) {
            float v = sq[i];
            v += __shfl_xor(v, 16); v += __shfl_xor(v, 32);
            if (lane < 16) S2o[wr * 32 + i * 16 + l15] = v;
        }
    }
    if (dok) {
#pragma unroll
        for (int j = 0; j < 2; j++) {
            float v = sk[j];
            v += __shfl_xor(v, 16); v += __shfl_xor(v, 32);
            if (lane < 16) S2o[96 + wc * 32 + j * 16 + l15] = v;
        }
    }
    ushort* So = S + ((size_t)ch * 64 + bh) * (DH * DH);
#pragma unroll
    for (int i = 0; i < 2; i++)
#pragma unroll
        for (int j = 0; j < 2; j++) {
            int e = wc * 32 + j * 16 + l15;
#pragma unroll
            for (int qq = 0; qq < 4; qq++) {
                int d = wr * 32 + i * 16 + k8 * 4 + qq;
                So[d * DH + e] = f2bf(acc[i][j][qq]);
            }
        }
}

// ---------------- attn finish: chunk-reduce + softmax + W2 GEMM (fused) ----
// grid (64): bh. 576 threads (9 waves).
// Phase A: softmax of [96][96], attn^T kept in LDS (pitch 104 vs bank aliasing)
// Phase B: 8 waves x (2 passes of 48 o-rows): W2[b][o][h*96+e] via MFMA.
__global__ __launch_bounds__(576) void attn_finish_kernel(
    const ushort* __restrict__ S, const float* __restrict__ S2,
    const float* __restrict__ temp, const ushort* __restrict__ pwb,
    ushort* __restrict__ W2) {
    int bh = blockIdx.x;
    int b_ = bh >> 3, h = bh & 7;
    int tid = threadIdx.x;
    __shared__ float rkv[96];
    __shared__ float red[96][6], red2[96][6];
    __shared__ ushort atl[96][104];   // [e][d], padded pitch
    int r = tid % 96, p = tid / 96;   // row d, col-group of 16
    if (tid < 96) {
        float sum = 0.f;
#pragma unroll 1
        for (int ch = 0; ch < 8; ch++)
            sum += S2[((size_t)ch * 64 + bh) * 192 + 96 + tid];
        rkv[tid] = 1.0f / fmaxf(sqrtf(sum), 1e-12f);
    }
    float sqd = 0.f;
#pragma unroll 1
    for (int ch = 0; ch < 8; ch++)
        sqd += S2[((size_t)ch * 64 + bh) * 192 + r];
    float rqd = 1.0f / fmaxf(sqrtf(sqd), 1e-12f);
    float v[16];
#pragma unroll
    for (int u = 0; u < 16; u++) v[u] = 0.f;
#pragma unroll 1
    for (int ch = 0; ch < 8; ch++) {
        const ushort* So = S + ((size_t)ch * 64 + bh) * (DH * DH) + r * DH + p * 16;
        short8 w0 = *(const short8*)So;
        short8 w1 = *(const short8*)(So + 8);
#pragma unroll
        for (int u = 0; u < 8; u++) {
            v[u] += bf2f((ushort)w0[u]);
            v[8 + u] += bf2f((ushort)w1[u]);
        }
    }
    __syncthreads();   // rkv ready
    float sd = rqd * temp[h];
#pragma unroll
    for (int u = 0; u < 16; u++) v[u] *= sd * rkv[p * 16 + u];
    float lm = v[0];
#pragma unroll
    for (int u = 1; u < 16; u++) lm = fmaxf(lm, v[u]);
    red[r][p] = lm;
    __syncthreads();
    float m = red[r][0];
#pragma unroll
    for (int u = 1; u < 6; u++) m = fmaxf(m, red[r][u]);
    float s = 0.f;
#pragma unroll
    for (int u = 0; u < 16; u++) { v[u] = __expf(v[u] - m); s += v[u]; }
    red2[r][p] = s;
    __syncthreads();
    float tot = red2[r][0];
#pragma unroll
    for (int u = 1; u < 6; u++) tot += red2[r][u];
    float inv = 1.0f / tot;
#pragma unroll
    for (int u = 0; u < 16; u++)
        atl[p * 16 + u][r] = f2bf(v[u] * inv);
    __syncthreads();
    // ---- Phase B: W2[b][o][h*96+e] = sum_d pw[o][h*96+d] * attn[d][e] ----
    int wid = tid >> 6, lane = tid & 63;
    if (wid < 8) {
        int k8 = lane >> 4, l15 = lane & 15;
        ushort* wo = W2 + (size_t)b_ * DIMC * DIMC + (size_t)h * DH;
#pragma unroll
        for (int pass = 0; pass < 2; pass++) {
            int o0 = wid * 96 + pass * 48;
            f32x4 acc[3][6] = {};
#pragma unroll
            for (int kk = 0; kk < DH; kk += 32) {
                short8 af[3], bf[6];
#pragma unroll
                for (int mm = 0; mm < 3; mm++)
                    af[mm] = *(const short8*)&pwb[(size_t)(o0 + mm * 16 + l15) * DIMC
                                                  + h * DH + kk + k8 * 8];
#pragma unroll
                for (int n = 0; n < 6; n++)
                    bf[n] = *(const short8*)&atl[n * 16 + l15][kk + k8 * 8];
#pragma unroll
                for (int mm = 0; mm < 3; mm++)
#pragma unroll
                    for (int n = 0; n < 6; n++)
                        acc[mm][n] = __builtin_amdgcn_mfma_f32_16x16x32_bf16(
                            af[mm], bf[n], acc[mm][n], 0, 0, 0);
            }
#pragma unroll
            for (int mm = 0; mm < 3; mm++) {
                int orow = o0 + mm * 16 + k8 * 4;
#pragma unroll
                for (int n = 0; n < 6; n++) {
                    int e = n * 16 + l15;
#pragma unroll
                    for (int qq = 0; qq < 4; qq++)
                        wo[(size_t)(orow + qq) * DIMC + e] = f2bf(acc[mm][n][qq]);
                }
            }
        }
    }
}

// ---------------- vproj: out = g1*(v·W2[b]^T + pb) + x  (256x256 BK=32) ----
__global__ __launch_bounds__(512) void vproj_kernel(
    const ushort* __restrict__ vb, const ushort* __restrict__ W2,
    const float* __restrict__ pb, const float* __restrict__ g1,
    const float* __restrict__ x, float* __restrict__ out) {
    __shared__ __align__(16) char lds[65536];
    int orig = blockIdx.x;                   // 0..383
    int wg = (orig & 7) * 48 + (orig >> 3);
    int b_ = wg / 48, rem = wg % 48, mt = rem / 3, ntl = rem % 3;
    int tok0 = b_ * NPB + mt * 256, o0 = ntl * 256;
    f32x4 acc[8][4] = {};
    gemm256_core((const char*)(vb + (size_t)tok0 * DIMC),
                 (const char*)(W2 + (size_t)b_ * DIMC * DIMC + (size_t)o0 * DIMC),
                 lds, acc);

    int tid = threadIdx.x, lane = tid & 63, wid = tid >> 6;
    int wr = wid >> 2, wc = wid & 3;
    int k8 = lane >> 4, l15 = lane & 15;
#pragma unroll
    for (int m8 = 0; m8 < 8; m8++) {
        int r0 = tok0 + wr * 128 + m8 * 16 + k8 * 4;
#pragma unroll
        for (int n = 0; n < 4; n++) {
            int o = o0 + wc * 64 + n * 16 + l15;
            float pbo = pb[o], g1o = g1[o];
            f32x4 a = acc[m8][n];
#pragma unroll
            for (int qq = 0; qq < 4; qq++) {
                size_t idx = (size_t)(r0 + qq) * DIMC + o;
                out[idx] = g1o * (a[qq] + pbo) + x[idx];
            }
        }
    }
}

extern "C" void kernel_launch(void* const* d_in, const int* in_sizes, int n_in,
                              void* d_out, int out_size, void* d_ws, size_t ws_size,
                              hipStream_t stream) {
    const float* x     = (const float*)d_in[0];
    const float* qkvw  = (const float*)d_in[1];
    const float* projw = (const float*)d_in[2];
    const float* projb = (const float*)d_in[3];
    const float* lng   = (const float*)d_in[4];
    const float* lnb   = (const float*)d_in[5];
    const float* temp  = (const float*)d_in[6];
    const float* g1    = (const float*)d_in[7];
    float* out = (float*)d_out;

    char* w = (char*)d_ws;
    ushort* qb    = (ushort*)(w + 0);            // 50,331,648  [B,H,dh,N]
    ushort* kb    = (ushort*)(w + 50331648);     // 50,331,648
    ushort* vb    = (ushort*)(w + 100663296);    // 50,331,648  [T, C] token-major
    ushort* qwb   = (ushort*)(w + 150994944);    // 3,538,944  (dead after qkv)
    ushort* pwb   = (ushort*)(w + 154533888);    // 1,179,648
    float*  S2    = (float*)(w + 155713536);     // 393,216 sumsq partials
    ushort* W2    = qb;                          // 9,437,184 (aliases dead qb)
    ushort* xb    = (ushort*)d_out;              // LN output (dead before vproj)
    ushort* Sb    = (ushort*)((char*)d_out + 50331648);  // 9.4 MB bf16 partials

    hipLaunchKernelGGL(prep_fused_kernel, dim3(9920), dim3(256), 0, stream,
                       qkvw, projw, qwb, pwb, x, lng, lnb, xb);
    hipLaunchKernelGGL(gemm_qkv_kernel, dim3(1152), dim3(512), 0, stream,
                       xb, qwb, qb, kb, vb);
    hipLaunchKernelGGL(attn_qk_kernel, dim3(64, 8), dim3(576), 0, stream,
                       qb, kb, Sb, S2);
    hipLaunchKernelGGL(attn_finish_kernel, dim3(64), dim3(576), 0, stream,
                       Sb, S2, temp, pwb, W2);
    hipLaunchKernelGGL(vproj_kernel, dim3(384), dim3(512), 0, stream,
                       vb, W2, projb, g1, x, out);
}

// Round 12
// 243.364 us; speedup vs baseline: 2.0963x; 1.0416x over previous
//
#include <hip/hip_runtime.h>
#include <hip/hip_bf16.h>
#include <stdint.h>

typedef __attribute__((ext_vector_type(8))) short short8;
typedef __attribute__((ext_vector_type(4))) float f32x4;
typedef __attribute__((ext_vector_type(4))) unsigned short us4;

#define DIMC 768
#define NTOK 32768
#define NPB 4096
#define HEADS 8
#define DH 96

__device__ __forceinline__ ushort f2bf(float f) {
    union { float f; uint32_t u; } c; c.f = f;
    uint32_t u = c.u;
    u += 0x7fffu + ((u >> 16) & 1u);
    return (ushort)(u >> 16);
}
__device__ __forceinline__ float bf2f(ushort h) {
    union { uint32_t u; float f; } c; c.u = ((uint32_t)h) << 16;
    return c.f;
}

__device__ __forceinline__ void gload_lds16(const void* g, void* l) {
    __builtin_amdgcn_global_load_lds(
        (const __attribute__((address_space(1))) void*)g,
        (__attribute__((address_space(3))) void*)l, 16, 0, 0);
}

// =====================================================================
// 256x256-tile BK=32 GEMM core (R10-measured; used by vproj which sits at
// its HBM floor). m201-style 4-phase/2-K-tile schedule, race-fixed vmcnt.
// =====================================================================
__device__ __forceinline__ void gemm256_core(
    const char* aglob, const char* bglob, char* lds, f32x4 (&acc)[8][4]) {
    const int tid = threadIdx.x;
    const int lane = tid & 63, wid = tid >> 6;
    const int wr = wid >> 2, wc = wid & 3;
    const int k8 = lane >> 4, l15 = lane & 15;

    const int L0 = tid * 16, L1 = (512 + tid) * 16;
    const int S0 = L0 ^ (((L0 >> 9) & 1) << 5);
    const int S1 = L1 ^ (((L1 >> 9) & 1) << 5);
    const int sr0 = S0 >> 6, sc0 = S0 & 63;
    const int sr1 = S1 >> 6, sc1 = S1 & 63;

    int aoff[8], boff[4];
#pragma unroll
    for (int m = 0; m < 8; m++) {
        int row = wr * 128 + m * 16 + l15;
        int o = row * 64 + k8 * 16;
        aoff[m] = o ^ (((o >> 9) & 1) << 5);
    }
#pragma unroll
    for (int n = 0; n < 4; n++) {
        int row = wc * 64 + n * 16 + l15;
        int o = row * 64 + k8 * 16;
        boff[n] = o ^ (((o >> 9) & 1) << 5);
    }

#define STG_A(kt, c) do {                                     \
        const char* ak_ = aglob + (size_t)(kt) * 64;          \
        char* al_ = lds + (c) * 16384;                        \
        gload_lds16(ak_ + sr0 * 1536 + sc0, al_ + L0);        \
        gload_lds16(ak_ + sr1 * 1536 + sc1, al_ + L1);        \
    } while (0)
#define STG_B(kt, c) do {                                     \
        const char* bk_ = bglob + (size_t)(kt) * 64;          \
        char* bl_ = lds + 32768 + (c) * 16384;                \
        gload_lds16(bk_ + sr0 * 1536 + sc0, bl_ + L0);        \
        gload_lds16(bk_ + sr1 * 1536 + sc1, bl_ + L1);        \
    } while (0)
#define MFMA16(mb)                                                                 \
    __builtin_amdgcn_s_setprio(1);                                                 \
    _Pragma("unroll")                                                              \
    for (int m_ = 0; m_ < 4; m_++)                                                 \
        _Pragma("unroll")                                                          \
        for (int n_ = 0; n_ < 4; n_++)                                             \
            acc[(mb) + m_][n_] = __builtin_amdgcn_mfma_f32_16x16x32_bf16(          \
                af[m_], bf[n_], acc[(mb) + m_][n_], 0, 0, 0);                      \
    __builtin_amdgcn_s_setprio(0);
#define BAR  asm volatile("s_barrier" ::: "memory")
#define LGKM0 do { asm volatile("s_waitcnt lgkmcnt(0)" ::: "memory"); \
                   __builtin_amdgcn_sched_barrier(0); } while (0)

    STG_B(0, 0); STG_A(0, 0); STG_B(1, 1);
    asm volatile("s_waitcnt vmcnt(2)" ::: "memory");
    BAR;

    const char* a0 = lds;
    const char* a1 = lds + 16384;
    const char* b0 = lds + 32768;
    const char* b1 = lds + 49152;

#pragma unroll
    for (int i = 0; i < 6; ++i) {
        short8 af[4], bf[4];
#pragma unroll
        for (int n = 0; n < 4; n++) bf[n] = *(const short8*)(b0 + boff[n]);
#pragma unroll
        for (int m = 0; m < 4; m++) af[m] = *(const short8*)(a0 + aoff[m]);
        STG_A(2 * i + 1, 1);
        BAR;
        LGKM0;
        MFMA16(0)
        BAR;
#pragma unroll
        for (int m = 0; m < 4; m++) af[m] = *(const short8*)(a0 + aoff[4 + m]);
        if (2 * i + 2 < 12) STG_B(2 * i + 2, 0);
        BAR;
        LGKM0;
        MFMA16(4)
        if (i < 5) asm volatile("s_waitcnt vmcnt(2)" ::: "memory");
        else       asm volatile("s_waitcnt vmcnt(0)" ::: "memory");
        BAR;
#pragma unroll
        for (int n = 0; n < 4; n++) bf[n] = *(const short8*)(b1 + boff[n]);
#pragma unroll
        for (int m = 0; m < 4; m++) af[m] = *(const short8*)(a1 + aoff[m]);
        if (2 * i + 2 < 12) STG_A(2 * i + 2, 0);
        BAR;
        LGKM0;
        MFMA16(0)
        BAR;
#pragma unroll
        for (int m = 0; m < 4; m++) af[m] = *(const short8*)(a1 + aoff[4 + m]);
        if (2 * i + 3 < 12) STG_B(2 * i + 3, 1);
        BAR;
        LGKM0;
        MFMA16(4)
        if (i < 5) {
            asm volatile("s_waitcnt vmcnt(2)" ::: "memory");
            BAR;
        }
    }
#undef STG_A
#undef STG_B
#undef MFMA16
#undef BAR
#undef LGKM0
}

// ---------------- fused prep: weight bf16 casts + LayerNorm cast -----------
__global__ __launch_bounds__(256) void prep_fused_kernel(
    const float* __restrict__ qw, const float* __restrict__ pw,
    ushort* __restrict__ qwb, ushort* __restrict__ pwb,
    const float* __restrict__ x, const float* __restrict__ g,
    const float* __restrict__ b, ushort* __restrict__ xb) {
    int bid = blockIdx.x;
    if (bid < 1728) {
        int i4 = (bid * 256 + threadIdx.x) * 4;
        if (i4 < 3 * DIMC * DIMC) {
            float4 w = *(const float4*)&qw[i4];
            us4 o;
            o[0] = f2bf(w.x); o[1] = f2bf(w.y); o[2] = f2bf(w.z); o[3] = f2bf(w.w);
            *(us4*)&qwb[i4] = o;
        }
        if (i4 < DIMC * DIMC) {
            float4 w = *(const float4*)&pw[i4];
            us4 o;
            o[0] = f2bf(w.x); o[1] = f2bf(w.y); o[2] = f2bf(w.z); o[3] = f2bf(w.w);
            *(us4*)&pwb[i4] = o;
        }
        return;
    }
    int t = (bid - 1728) * 4 + (threadIdx.x >> 6);
    int lane = threadIdx.x & 63;
    const float* xr = x + (size_t)t * DIMC;
    float4 v[3];
    float s = 0.f, s2 = 0.f;
#pragma unroll
    for (int u = 0; u < 3; u++) {
        v[u] = *(const float4*)&xr[u * 256 + lane * 4];
        s  += v[u].x + v[u].y + v[u].z + v[u].w;
        s2 += v[u].x * v[u].x + v[u].y * v[u].y + v[u].z * v[u].z + v[u].w * v[u].w;
    }
#pragma unroll
    for (int off = 32; off > 0; off >>= 1) {
        s  += __shfl_down(s, off);
        s2 += __shfl_down(s2, off);
    }
    s = __shfl(s, 0);
    s2 = __shfl(s2, 0);
    float mean = s * (1.0f / DIMC);
    float rstd = rsqrtf(s2 * (1.0f / DIMC) - mean * mean + 1e-5f);
    ushort* xo = xb + (size_t)t * DIMC;
#pragma unroll
    for (int u = 0; u < 3; u++) {
        float4 gv = *(const float4*)&g[u * 256 + lane * 4];
        float4 bv = *(const float4*)&b[u * 256 + lane * 4];
        us4 o;
        o[0] = f2bf((v[u].x - mean) * rstd * gv.x + bv.x);
        o[1] = f2bf((v[u].y - mean) * rstd * gv.y + bv.y);
        o[2] = f2bf((v[u].z - mean) * rstd * gv.z + bv.z);
        o[3] = f2bf((v[u].w - mean) * rstd * gv.w + bv.w);
        *(us4*)&xo[u * 256 + lane * 4] = o;
    }
}

// ---------------- QKV GEMM: 128x256 tile, 48 KiB LDS -> 3 blocks/CU --------
// 8 waves (2Mx4N), each 64x64. Same race-verified 4-phase/2-K-tile schedule;
// load ledger: STG_A=1, STG_B=2 loads; vmcnt(2) at Ph2/Ph4 ends.
__global__ __launch_bounds__(512) void gemm_qkv_kernel(
    const ushort* __restrict__ xb, const ushort* __restrict__ wb,
    ushort* __restrict__ qb, ushort* __restrict__ kb, ushort* __restrict__ vb) {
    __shared__ __align__(16) char lds[49152];
    int orig = blockIdx.x;                   // 0..2303
    int wg = (orig & 7) * 288 + (orig >> 3);
    int nt = wg % 9, mt = wg / 9;
    int m0 = mt * 128, n0 = nt * 256;
    const char* aglob = (const char*)(xb + (size_t)m0 * DIMC);
    const char* bglob = (const char*)(wb + (size_t)n0 * DIMC);

    const int tid = threadIdx.x;
    const int lane = tid & 63, wid = tid >> 6;
    const int wr = wid >> 2, wc = wid & 3;
    const int k8 = lane >> 4, l15 = lane & 15;

    // A staging: 8 KB/tile -> 1 load/thread. B staging: 16 KB -> 2 loads.
    const int LA = tid * 16;                       // 0..8191
    const int SA = LA ^ (((LA >> 9) & 1) << 5);
    const int sra = SA >> 6, sca = SA & 63;
    const int L0 = tid * 16, L1 = (512 + tid) * 16;
    const int S0 = L0 ^ (((L0 >> 9) & 1) << 5);
    const int S1 = L1 ^ (((L1 >> 9) & 1) << 5);
    const int sr0 = S0 >> 6, sc0 = S0 & 63;
    const int sr1 = S1 >> 6, sc1 = S1 & 63;

    int aoff[4], boff[4];
#pragma unroll
    for (int m = 0; m < 4; m++) {
        int row = wr * 64 + m * 16 + l15;          // 0..127
        int o = row * 64 + k8 * 16;
        aoff[m] = o ^ (((o >> 9) & 1) << 5);
    }
#pragma unroll
    for (int n = 0; n < 4; n++) {
        int row = wc * 64 + n * 16 + l15;          // 0..255
        int o = row * 64 + k8 * 16;
        boff[n] = o ^ (((o >> 9) & 1) << 5);
    }

#define QSTG_A(kt, c) do {                                    \
        const char* ak_ = aglob + (size_t)(kt) * 64;          \
        char* al_ = lds + (c) * 8192;                         \
        gload_lds16(ak_ + sra * 1536 + sca, al_ + LA);        \
    } while (0)
#define QSTG_B(kt, c) do {                                    \
        const char* bk_ = bglob + (size_t)(kt) * 64;          \
        char* bl_ = lds + 16384 + (c) * 16384;                \
        gload_lds16(bk_ + sr0 * 1536 + sc0, bl_ + L0);        \
        gload_lds16(bk_ + sr1 * 1536 + sc1, bl_ + L1);        \
    } while (0)
#define QMFMA8(mb)                                                                 \
    __builtin_amdgcn_s_setprio(1);                                                 \
    _Pragma("unroll")                                                              \
    for (int m_ = 0; m_ < 2; m_++)                                                 \
        _Pragma("unroll")                                                          \
        for (int n_ = 0; n_ < 4; n_++)                                             \
            acc[(mb) + m_][n_] = __builtin_amdgcn_mfma_f32_16x16x32_bf16(          \
                af[m_], bf[n_], acc[(mb) + m_][n_], 0, 0, 0);                      \
    __builtin_amdgcn_s_setprio(0);
#define BAR  asm volatile("s_barrier" ::: "memory")
#define LGKM0 do { asm volatile("s_waitcnt lgkmcnt(0)" ::: "memory"); \
                   __builtin_amdgcn_sched_barrier(0); } while (0)

    f32x4 acc[4][4] = {};
    const char* a0 = lds;
    const char* a1 = lds + 8192;
    const char* b0 = lds + 16384;
    const char* b1 = lds + 32768;

    // prologue: B0,A0 drained; B1 (2 loads) in flight
    QSTG_B(0, 0); QSTG_A(0, 0); QSTG_B(1, 1);
    asm volatile("s_waitcnt vmcnt(2)" ::: "memory");
    BAR;

#pragma unroll
    for (int i = 0; i < 6; ++i) {
        short8 af[2], bf[4];
        // ---- Ph1: tile 2i (buf0), m0-1 ----
#pragma unroll
        for (int n = 0; n < 4; n++) bf[n] = *(const short8*)(b0 + boff[n]);
#pragma unroll
        for (int m = 0; m < 2; m++) af[m] = *(const short8*)(a0 + aoff[m]);
        QSTG_A(2 * i + 1, 1);
        BAR;
        LGKM0;
        QMFMA8(0)
        BAR;
        // ---- Ph2: tile 2i (buf0), m2-3 ----
#pragma unroll
        for (int m = 0; m < 2; m++) af[m] = *(const short8*)(a0 + aoff[2 + m]);
        if (2 * i + 2 < 12) QSTG_B(2 * i + 2, 0);
        BAR;
        LGKM0;
        QMFMA8(2)
        // in flight: {B(2i+1):2, A(2i+1):1, B(2i+2):2} -> drain first 3
        if (i < 5) asm volatile("s_waitcnt vmcnt(2)" ::: "memory");
        else       asm volatile("s_waitcnt vmcnt(0)" ::: "memory");
        BAR;
        // ---- Ph3: tile 2i+1 (buf1), m0-1 ----
#pragma unroll
        for (int n = 0; n < 4; n++) bf[n] = *(const short8*)(b1 + boff[n]);
#pragma unroll
        for (int m = 0; m < 2; m++) af[m] = *(const short8*)(a1 + aoff[m]);
        if (2 * i + 2 < 12) QSTG_A(2 * i + 2, 0);
        BAR;
        LGKM0;
        QMFMA8(0)
        BAR;
        // ---- Ph4: tile 2i+1 (buf1), m2-3 ----
#pragma unroll
        for (int m = 0; m < 2; m++) af[m] = *(const short8*)(a1 + aoff[2 + m]);
        if (2 * i + 3 < 12) QSTG_B(2 * i + 3, 1);
        BAR;
        LGKM0;
        QMFMA8(2)
        if (i < 5) {
            // in flight: {B(2i+2):2, A(2i+2):1, B(2i+3):2} -> drain first 3
            asm volatile("s_waitcnt vmcnt(2)" ::: "memory");
            BAR;
        }
    }
#undef QSTG_A
#undef QSTG_B
#undef QMFMA8
#undef BAR
#undef LGKM0

    int seg = n0 / DIMC;                     // 0=q, 1=k, 2=v (no straddle)
#pragma unroll
    for (int m8 = 0; m8 < 4; m8++) {
        int r0 = m0 + wr * 64 + m8 * 16 + k8 * 4;
        int b_ = r0 >> 12, nn = r0 & (NPB - 1);
#pragma unroll
        for (int n = 0; n < 4; n++) {
            int o = n0 + wc * 64 + n * 16 + l15;
            f32x4 a = acc[m8][n];
            if (seg == 2) {
                int oL = o - 2 * DIMC;
#pragma unroll
                for (int qq = 0; qq < 4; qq++)
                    vb[(size_t)(r0 + qq) * DIMC + oL] = f2bf(a[qq]);
            } else {
                int oL = o - seg * DIMC;
                int h = oL / DH, d = oL - h * DH;
                us4 pk;
#pragma unroll
                for (int qq = 0; qq < 4; qq++) pk[qq] = f2bf(a[qq]);
                *(us4*)((seg ? kb : qb) +
                        ((size_t)(b_ * HEADS + h) * DH + d) * NPB + nn) = pk;
            }
        }
    }
}

// ---------------- attn partial: S[ch][bh][96][96] (bf16) + sumsq partials --
__global__ __launch_bounds__(576) void attn_qk_kernel(
    const ushort* __restrict__ qb, const ushort* __restrict__ kb,
    ushort* __restrict__ S, float* __restrict__ S2) {
    int bh = blockIdx.x, ch = blockIdx.y;
    int tid = threadIdx.x, wid = tid >> 6, lane = tid & 63;
    int wr = wid / 3, wc = wid - wr * 3;
    int k8 = lane >> 4, l15 = lane & 15;
    const ushort* qrow = qb + (size_t)bh * DH * NPB + ch * 512;
    const ushort* krow = kb + (size_t)bh * DH * NPB + ch * 512;
    bool doq = (wc == 0), dok = (wr == 0);
    f32x4 acc[2][2] = {};
    float sq[2] = {0.f, 0.f}, sk[2] = {0.f, 0.f};
    for (int n = 0; n < 512; n += 32) {
        short8 a[2], b[2];
#pragma unroll
        for (int i = 0; i < 2; i++)
            a[i] = *(const short8*)&qrow[(size_t)(wr * 32 + i * 16 + l15) * NPB + n + k8 * 8];
#pragma unroll
        for (int j = 0; j < 2; j++)
            b[j] = *(const short8*)&krow[(size_t)(wc * 32 + j * 16 + l15) * NPB + n + k8 * 8];
        if (doq) {
#pragma unroll
            for (int i = 0; i < 2; i++)
#pragma unroll
                for (int u = 0; u < 8; u++) {
                    float f = bf2f((ushort)a[i][u]); sq[i] += f * f;
                }
        }
        if (dok) {
#pragma unroll
            for (int j = 0; j < 2; j++)
#pragma unroll
                for (int u = 0; u < 8; u++) {
                    float f = bf2f((ushort)b[j][u]); sk[j] += f * f;
                }
        }
#pragma unroll
        for (int i = 0; i < 2; i++)
#pragma unroll
            for (int j = 0; j < 2; j++)
                acc[i][j] = __builtin_amdgcn_mfma_f32_16x16x32_bf16(a[i], b[j], acc[i][j], 0, 0, 0);
    }
    float* S2o = S2 + ((size_t)ch * 64 + bh) * 192;
    if (doq) {
#pragma unroll
        for (int i = 0; i < 2; i++) {
            float v = sq[i];
            v += __shfl_xor(v, 16); v += __shfl_xor(v, 32);
            if (lane < 16) S2o[wr * 32 + i * 16 + l15] = v;
        }
    }
    if (dok) {
#pragma unroll
        for (int j = 0; j < 2; j++) {
            float v = sk[j];
            v += __shfl_xor(v, 16); v += __shfl_xor(v, 32);
            if (lane < 16) S2o[96 + wc * 32 + j * 16 + l15] = v;
        }
    }
    ushort* So = S + ((size_t)ch * 64 + bh) * (DH * DH);
#pragma unroll
    for (int i = 0; i < 2; i++)
#pragma unroll
        for (int j = 0; j < 2; j++) {
            int e = wc * 32 + j * 16 + l15;
#pragma unroll
            for (int qq = 0; qq < 4; qq++) {
                int d = wr * 32 + i * 16 + k8 * 4 + qq;
                So[d * DH + e] = f2bf(acc[i][j][qq]);
            }
        }
}

// ---------------- attn finish: chunk-reduce + softmax + W2 GEMM (fused) ----
__global__ __launch_bounds__(576) void attn_finish_kernel(
    const ushort* __restrict__ S, const float* __restrict__ S2,
    const float* __restrict__ temp, const ushort* __restrict__ pwb,
    ushort* __restrict__ W2) {
    int bh = blockIdx.x;
    int b_ = bh >> 3, h = bh & 7;
    int tid = threadIdx.x;
    __shared__ float rkv[96];
    __shared__ float red[96][6], red2[96][6];
    __shared__ ushort atl[96][104];   // [e][d], padded pitch
    int r = tid % 96, p = tid / 96;   // row d, col-group of 16
    if (tid < 96) {
        float sum = 0.f;
#pragma unroll 1
        for (int ch = 0; ch < 8; ch++)
            sum += S2[((size_t)ch * 64 + bh) * 192 + 96 + tid];
        rkv[tid] = 1.0f / fmaxf(sqrtf(sum), 1e-12f);
    }
    float sqd = 0.f;
#pragma unroll 1
    for (int ch = 0; ch < 8; ch++)
        sqd += S2[((size_t)ch * 64 + bh) * 192 + r];
    float rqd = 1.0f / fmaxf(sqrtf(sqd), 1e-12f);
    float v[16];
#pragma unroll
    for (int u = 0; u < 16; u++) v[u] = 0.f;
#pragma unroll 1
    for (int ch = 0; ch < 8; ch++) {
        const ushort* So = S + ((size_t)ch * 64 + bh) * (DH * DH) + r * DH + p * 16;
        short8 w0 = *(const short8*)So;
        short8 w1 = *(const short8*)(So + 8);
#pragma unroll
        for (int u = 0; u < 8; u++) {
            v[u] += bf2f((ushort)w0[u]);
            v[8 + u] += bf2f((ushort)w1[u]);
        }
    }
    __syncthreads();   // rkv ready
    float sd = rqd * temp[h];
#pragma unroll
    for (int u = 0; u < 16; u++) v[u] *= sd * rkv[p * 16 + u];
    float lm = v[0];
#pragma unroll
    for (int u = 1; u < 16; u++) lm = fmaxf(lm, v[u]);
    red[r][p] = lm;
    __syncthreads();
    float m = red[r][0];
#pragma unroll
    for (int u = 1; u < 6; u++) m = fmaxf(m, red[r][u]);
    float s = 0.f;
#pragma unroll
    for (int u = 0; u < 16; u++) { v[u] = __expf(v[u] - m); s += v[u]; }
    red2[r][p] = s;
    __syncthreads();
    float tot = red2[r][0];
#pragma unroll
    for (int u = 1; u < 6; u++) tot += red2[r][u];
    float inv = 1.0f / tot;
#pragma unroll
    for (int u = 0; u < 16; u++)
        atl[p * 16 + u][r] = f2bf(v[u] * inv);
    __syncthreads();
    // ---- Phase B: W2[b][o][h*96+e] = sum_d pw[o][h*96+d] * attn[d][e] ----
    int wid = tid >> 6, lane = tid & 63;
    if (wid < 8) {
        int k8 = lane >> 4, l15 = lane & 15;
        ushort* wo = W2 + (size_t)b_ * DIMC * DIMC + (size_t)h * DH;
#pragma unroll
        for (int pass = 0; pass < 2; pass++) {
            int o0 = wid * 96 + pass * 48;
            f32x4 acc[3][6] = {};
#pragma unroll
            for (int kk = 0; kk < DH; kk += 32) {
                short8 af[3], bf[6];
#pragma unroll
                for (int mm = 0; mm < 3; mm++)
                    af[mm] = *(const short8*)&pwb[(size_t)(o0 + mm * 16 + l15) * DIMC
                                                  + h * DH + kk + k8 * 8];
#pragma unroll
                for (int n = 0; n < 6; n++)
                    bf[n] = *(const short8*)&atl[n * 16 + l15][kk + k8 * 8];
#pragma unroll
                for (int mm = 0; mm < 3; mm++)
#pragma unroll
                    for (int n = 0; n < 6; n++)
                        acc[mm][n] = __builtin_amdgcn_mfma_f32_16x16x32_bf16(
                            af[mm], bf[n], acc[mm][n], 0, 0, 0);
            }
#pragma unroll
            for (int mm = 0; mm < 3; mm++) {
                int orow = o0 + mm * 16 + k8 * 4;
#pragma unroll
                for (int n = 0; n < 6; n++) {
                    int e = n * 16 + l15;
#pragma unroll
                    for (int qq = 0; qq < 4; qq++)
                        wo[(size_t)(orow + qq) * DIMC + e] = f2bf(acc[mm][n][qq]);
                }
            }
        }
    }
}

// ---------------- vproj: out = g1*(v·W2[b]^T + pb) + x  (256x256 BK=32) ----
__global__ __launch_bounds__(512) void vproj_kernel(
    const ushort* __restrict__ vb, const ushort* __restrict__ W2,
    const float* __restrict__ pb, const float* __restrict__ g1,
    const float* __restrict__ x, float* __restrict__ out) {
    __shared__ __align__(16) char lds[65536];
    int orig = blockIdx.x;                   // 0..383
    int wg = (orig & 7) * 48 + (orig >> 3);
    int b_ = wg / 48, rem = wg % 48, mt = rem / 3, ntl = rem % 3;
    int tok0 = b_ * NPB + mt * 256, o0 = ntl * 256;
    f32x4 acc[8][4] = {};
    gemm256_core((const char*)(vb + (size_t)tok0 * DIMC),
                 (const char*)(W2 + (size_t)b_ * DIMC * DIMC + (size_t)o0 * DIMC),
                 lds, acc);

    int tid = threadIdx.x, lane = tid & 63, wid = tid >> 6;
    int wr = wid >> 2, wc = wid & 3;
    int k8 = lane >> 4, l15 = lane & 15;
#pragma unroll
    for (int m8 = 0; m8 < 8; m8++) {
        int r0 = tok0 + wr * 128 + m8 * 16 + k8 * 4;
#pragma unroll
        for (int n = 0; n < 4; n++) {
            int o = o0 + wc * 64 + n * 16 + l15;
            float pbo = pb[o], g1o = g1[o];
            f32x4 a = acc[m8][n];
#pragma unroll
            for (int qq = 0; qq < 4; qq++) {
                size_t idx = (size_t)(r0 + qq) * DIMC + o;
                out[idx] = g1o * (a[qq] + pbo) + x[idx];
            }
        }
    }
}

extern "C" void kernel_launch(void* const* d_in, const int* in_sizes, int n_in,
                              void* d_out, int out_size, void* d_ws, size_t ws_size,
                              hipStream_t stream) {
    const float* x     = (const float*)d_in[0];
    const float* qkvw  = (const float*)d_in[1];
    const float* projw = (const float*)d_in[2];
    const float* projb = (const float*)d_in[3];
    const float* lng   = (const float*)d_in[4];
    const float* lnb   = (const float*)d_in[5];
    const float* temp  = (const float*)d_in[6];
    const float* g1    = (const float*)d_in[7];
    float* out = (float*)d_out;

    char* w = (char*)d_ws;
    ushort* qb    = (ushort*)(w + 0);            // 50,331,648  [B,H,dh,N]
    ushort* kb    = (ushort*)(w + 50331648);     // 50,331,648
    ushort* vb    = (ushort*)(w + 100663296);    // 50,331,648  [T, C] token-major
    ushort* qwb   = (ushort*)(w + 150994944);    // 3,538,944  (dead after qkv)
    ushort* pwb   = (ushort*)(w + 154533888);    // 1,179,648
    float*  S2    = (float*)(w + 155713536);     // 393,216 sumsq partials
    ushort* W2    = qb;                          // 9,437,184 (aliases dead qb)
    ushort* xb    = (ushort*)d_out;              // LN output (dead before vproj)
    ushort* Sb    = (ushort*)((char*)d_out + 50331648);  // 9.4 MB bf16 partials

    hipLaunchKernelGGL(prep_fused_kernel, dim3(9920), dim3(256), 0, stream,
                       qkvw, projw, qwb, pwb, x, lng, lnb, xb);
    hipLaunchKernelGGL(gemm_qkv_kernel, dim3(2304), dim3(512), 0, stream,
                       xb, qwb, qb, kb, vb);
    hipLaunchKernelGGL(attn_qk_kernel, dim3(64, 8), dim3(576), 0, stream,
                       qb, kb, Sb, S2);
    hipLaunchKernelGGL(attn_finish_kernel, dim3(64), dim3(576), 0, stream,
                       Sb, S2, temp, pwb, W2);
    hipLaunchKernelGGL(vproj_kernel, dim3(384), dim3(512), 0, stream,
                       vb, W2, projb, g1, x, out);
}

// Round 13
// 232.220 us; speedup vs baseline: 2.1969x; 1.0480x over previous
//
#include <hip/hip_runtime.h>
#include <hip/hip_bf16.h>
#include <stdint.h>

typedef __attribute__((ext_vector_type(8))) short short8;
typedef __attribute__((ext_vector_type(4))) float f32x4;
typedef __attribute__((ext_vector_type(4))) unsigned short us4;

#define DIMC 768
#define NTOK 32768
#define NPB 4096
#define HEADS 8
#define DH 96

__device__ __forceinline__ ushort f2bf(float f) {
    union { float f; uint32_t u; } c; c.f = f;
    uint32_t u = c.u;
    u += 0x7fffu + ((u >> 16) & 1u);
    return (ushort)(u >> 16);
}
__device__ __forceinline__ float bf2f(ushort h) {
    union { uint32_t u; float f; } c; c.u = ((uint32_t)h) << 16;
    return c.f;
}

__device__ __forceinline__ void gload_lds16(const void* g, void* l) {
    __builtin_amdgcn_global_load_lds(
        (const __attribute__((address_space(1))) void*)g,
        (__attribute__((address_space(3))) void*)l, 16, 0, 0);
}

// =====================================================================
// 128x256-tile BK=32 GEMM core (R12-measured on qkv: 93us, 3 blocks/CU,
// occupancy 34%, 0 bank conflicts). 8 waves (2Mx4N), each 64x64 output.
// LDS 48 KiB: A[2][128][32] + B[2][256][32] bf16, st_16x32 swizzle,
// linear gload_lds dest + pre-swizzled global source + swizzled ds_read.
// m201-style 4-phase/2-K-tile schedule, race-fixed counted vmcnt:
//  Ph1: read b0,a0[0-1]; STG A(2i+1)->buf1; BAR; lgkm0; MFMA; BAR
//  Ph2: read a0[2-3];    STG B(2i+2)->buf0; BAR; lgkm0; MFMA; vm(2); BAR
//  Ph3: read b1,a1[0-1]; STG A(2i+2)->buf0; BAR; lgkm0; MFMA; BAR
//  Ph4: read a1[2-3];    STG B(2i+3)->buf1; BAR; lgkm0; MFMA; vm(2); BAR
// Ledger (A=1 load, B=2): end-Ph2 in flight {B(2i+1):2,A(2i+1):1,B(2i+2):2}
// -> vm(2) drains first 3; end-Ph4 {B(2i+2):2,A(2i+2):1,B(2i+3):2} -> vm(2).
// Global row stride fixed 1536 B (=768 ch * 2 B).
// =====================================================================
__device__ __forceinline__ void gemm128_core(
    const char* aglob, const char* bglob, char* lds, f32x4 (&acc)[4][4]) {
    const int tid = threadIdx.x;
    const int lane = tid & 63, wid = tid >> 6;
    const int wr = wid >> 2, wc = wid & 3;
    const int k8 = lane >> 4, l15 = lane & 15;

    const int LA = tid * 16;
    const int SA = LA ^ (((LA >> 9) & 1) << 5);
    const int sra = SA >> 6, sca = SA & 63;
    const int L0 = tid * 16, L1 = (512 + tid) * 16;
    const int S0 = L0 ^ (((L0 >> 9) & 1) << 5);
    const int S1 = L1 ^ (((L1 >> 9) & 1) << 5);
    const int sr0 = S0 >> 6, sc0 = S0 & 63;
    const int sr1 = S1 >> 6, sc1 = S1 & 63;

    int aoff[4], boff[4];
#pragma unroll
    for (int m = 0; m < 4; m++) {
        int row = wr * 64 + m * 16 + l15;          // 0..127
        int o = row * 64 + k8 * 16;
        aoff[m] = o ^ (((o >> 9) & 1) << 5);
    }
#pragma unroll
    for (int n = 0; n < 4; n++) {
        int row = wc * 64 + n * 16 + l15;          // 0..255
        int o = row * 64 + k8 * 16;
        boff[n] = o ^ (((o >> 9) & 1) << 5);
    }

#define QSTG_A(kt, c) do {                                    \
        const char* ak_ = aglob + (size_t)(kt) * 64;          \
        char* al_ = lds + (c) * 8192;                         \
        gload_lds16(ak_ + sra * 1536 + sca, al_ + LA);        \
    } while (0)
#define QSTG_B(kt, c) do {                                    \
        const char* bk_ = bglob + (size_t)(kt) * 64;          \
        char* bl_ = lds + 16384 + (c) * 16384;                \
        gload_lds16(bk_ + sr0 * 1536 + sc0, bl_ + L0);        \
        gload_lds16(bk_ + sr1 * 1536 + sc1, bl_ + L1);        \
    } while (0)
#define QMFMA8(mb)                                                                 \
    __builtin_amdgcn_s_setprio(1);                                                 \
    _Pragma("unroll")                                                              \
    for (int m_ = 0; m_ < 2; m_++)                                                 \
        _Pragma("unroll")                                                          \
        for (int n_ = 0; n_ < 4; n_++)                                             \
            acc[(mb) + m_][n_] = __builtin_amdgcn_mfma_f32_16x16x32_bf16(          \
                af[m_], bf[n_], acc[(mb) + m_][n_], 0, 0, 0);                      \
    __builtin_amdgcn_s_setprio(0);
#define BAR  asm volatile("s_barrier" ::: "memory")
#define LGKM0 do { asm volatile("s_waitcnt lgkmcnt(0)" ::: "memory"); \
                   __builtin_amdgcn_sched_barrier(0); } while (0)

    const char* a0 = lds;
    const char* a1 = lds + 8192;
    const char* b0 = lds + 16384;
    const char* b1 = lds + 32768;

    QSTG_B(0, 0); QSTG_A(0, 0); QSTG_B(1, 1);
    asm volatile("s_waitcnt vmcnt(2)" ::: "memory");
    BAR;

#pragma unroll
    for (int i = 0; i < 6; ++i) {
        short8 af[2], bf[4];
        // ---- Ph1: tile 2i (buf0), m0-1 ----
#pragma unroll
        for (int n = 0; n < 4; n++) bf[n] = *(const short8*)(b0 + boff[n]);
#pragma unroll
        for (int m = 0; m < 2; m++) af[m] = *(const short8*)(a0 + aoff[m]);
        QSTG_A(2 * i + 1, 1);
        BAR;
        LGKM0;
        QMFMA8(0)
        BAR;
        // ---- Ph2: tile 2i (buf0), m2-3 ----
#pragma unroll
        for (int m = 0; m < 2; m++) af[m] = *(const short8*)(a0 + aoff[2 + m]);
        if (2 * i + 2 < 12) QSTG_B(2 * i + 2, 0);
        BAR;
        LGKM0;
        QMFMA8(2)
        if (i < 5) asm volatile("s_waitcnt vmcnt(2)" ::: "memory");
        else       asm volatile("s_waitcnt vmcnt(0)" ::: "memory");
        BAR;
        // ---- Ph3: tile 2i+1 (buf1), m0-1 ----
#pragma unroll
        for (int n = 0; n < 4; n++) bf[n] = *(const short8*)(b1 + boff[n]);
#pragma unroll
        for (int m = 0; m < 2; m++) af[m] = *(const short8*)(a1 + aoff[m]);
        if (2 * i + 2 < 12) QSTG_A(2 * i + 2, 0);
        BAR;
        LGKM0;
        QMFMA8(0)
        BAR;
        // ---- Ph4: tile 2i+1 (buf1), m2-3 ----
#pragma unroll
        for (int m = 0; m < 2; m++) af[m] = *(const short8*)(a1 + aoff[2 + m]);
        if (2 * i + 3 < 12) QSTG_B(2 * i + 3, 1);
        BAR;
        LGKM0;
        QMFMA8(2)
        if (i < 5) {
            asm volatile("s_waitcnt vmcnt(2)" ::: "memory");
            BAR;
        }
    }
#undef QSTG_A
#undef QSTG_B
#undef QMFMA8
#undef BAR
#undef LGKM0
}

// ---------------- fused prep: weight bf16 casts + LayerNorm cast -----------
__global__ __launch_bounds__(256) void prep_fused_kernel(
    const float* __restrict__ qw, const float* __restrict__ pw,
    ushort* __restrict__ qwb, ushort* __restrict__ pwb,
    const float* __restrict__ x, const float* __restrict__ g,
    const float* __restrict__ b, ushort* __restrict__ xb) {
    int bid = blockIdx.x;
    if (bid < 1728) {
        int i4 = (bid * 256 + threadIdx.x) * 4;
        if (i4 < 3 * DIMC * DIMC) {
            float4 w = *(const float4*)&qw[i4];
            us4 o;
            o[0] = f2bf(w.x); o[1] = f2bf(w.y); o[2] = f2bf(w.z); o[3] = f2bf(w.w);
            *(us4*)&qwb[i4] = o;
        }
        if (i4 < DIMC * DIMC) {
            float4 w = *(const float4*)&pw[i4];
            us4 o;
            o[0] = f2bf(w.x); o[1] = f2bf(w.y); o[2] = f2bf(w.z); o[3] = f2bf(w.w);
            *(us4*)&pwb[i4] = o;
        }
        return;
    }
    int t = (bid - 1728) * 4 + (threadIdx.x >> 6);
    int lane = threadIdx.x & 63;
    const float* xr = x + (size_t)t * DIMC;
    float4 v[3];
    float s = 0.f, s2 = 0.f;
#pragma unroll
    for (int u = 0; u < 3; u++) {
        v[u] = *(const float4*)&xr[u * 256 + lane * 4];
        s  += v[u].x + v[u].y + v[u].z + v[u].w;
        s2 += v[u].x * v[u].x + v[u].y * v[u].y + v[u].z * v[u].z + v[u].w * v[u].w;
    }
#pragma unroll
    for (int off = 32; off > 0; off >>= 1) {
        s  += __shfl_down(s, off);
        s2 += __shfl_down(s2, off);
    }
    s = __shfl(s, 0);
    s2 = __shfl(s2, 0);
    float mean = s * (1.0f / DIMC);
    float rstd = rsqrtf(s2 * (1.0f / DIMC) - mean * mean + 1e-5f);
    ushort* xo = xb + (size_t)t * DIMC;
#pragma unroll
    for (int u = 0; u < 3; u++) {
        float4 gv = *(const float4*)&g[u * 256 + lane * 4];
        float4 bv = *(const float4*)&b[u * 256 + lane * 4];
        us4 o;
        o[0] = f2bf((v[u].x - mean) * rstd * gv.x + bv.x);
        o[1] = f2bf((v[u].y - mean) * rstd * gv.y + bv.y);
        o[2] = f2bf((v[u].z - mean) * rstd * gv.z + bv.z);
        o[3] = f2bf((v[u].w - mean) * rstd * gv.w + bv.w);
        *(us4*)&xo[u * 256 + lane * 4] = o;
    }
}

// ---------------- QKV GEMM: 128x256 tile, 48 KiB LDS -> 3 blocks/CU --------
__global__ __launch_bounds__(512) void gemm_qkv_kernel(
    const ushort* __restrict__ xb, const ushort* __restrict__ wb,
    ushort* __restrict__ qb, ushort* __restrict__ kb, ushort* __restrict__ vb) {
    __shared__ __align__(16) char lds[49152];
    int orig = blockIdx.x;                   // 0..2303
    int wg = (orig & 7) * 288 + (orig >> 3);
    int nt = wg % 9, mt = wg / 9;
    int m0 = mt * 128, n0 = nt * 256;
    f32x4 acc[4][4] = {};
    gemm128_core((const char*)(xb + (size_t)m0 * DIMC),
                 (const char*)(wb + (size_t)n0 * DIMC), lds, acc);

    const int tid = threadIdx.x;
    const int lane = tid & 63, wid = tid >> 6;
    const int wr = wid >> 2, wc = wid & 3;
    const int k8 = lane >> 4, l15 = lane & 15;
    int seg = n0 / DIMC;                     // 0=q, 1=k, 2=v (no straddle)
#pragma unroll
    for (int m8 = 0; m8 < 4; m8++) {
        int r0 = m0 + wr * 64 + m8 * 16 + k8 * 4;
        int b_ = r0 >> 12, nn = r0 & (NPB - 1);
#pragma unroll
        for (int n = 0; n < 4; n++) {
            int o = n0 + wc * 64 + n * 16 + l15;
            f32x4 a = acc[m8][n];
            if (seg == 2) {
                int oL = o - 2 * DIMC;
#pragma unroll
                for (int qq = 0; qq < 4; qq++)
                    vb[(size_t)(r0 + qq) * DIMC + oL] = f2bf(a[qq]);
            } else {
                int oL = o - seg * DIMC;
                int h = oL / DH, d = oL - h * DH;
                us4 pk;
#pragma unroll
                for (int qq = 0; qq < 4; qq++) pk[qq] = f2bf(a[qq]);
                *(us4*)((seg ? kb : qb) +
                        ((size_t)(b_ * HEADS + h) * DH + d) * NPB + nn) = pk;
            }
        }
    }
}

// ---------------- attn partial: S[ch][bh][96][96] (bf16) + sumsq partials --
__global__ __launch_bounds__(576) void attn_qk_kernel(
    const ushort* __restrict__ qb, const ushort* __restrict__ kb,
    ushort* __restrict__ S, float* __restrict__ S2) {
    int bh = blockIdx.x, ch = blockIdx.y;
    int tid = threadIdx.x, wid = tid >> 6, lane = tid & 63;
    int wr = wid / 3, wc = wid - wr * 3;
    int k8 = lane >> 4, l15 = lane & 15;
    const ushort* qrow = qb + (size_t)bh * DH * NPB + ch * 512;
    const ushort* krow = kb + (size_t)bh * DH * NPB + ch * 512;
    bool doq = (wc == 0), dok = (wr == 0);
    f32x4 acc[2][2] = {};
    float sq[2] = {0.f, 0.f}, sk[2] = {0.f, 0.f};
    for (int n = 0; n < 512; n += 32) {
        short8 a[2], b[2];
#pragma unroll
        for (int i = 0; i < 2; i++)
            a[i] = *(const short8*)&qrow[(size_t)(wr * 32 + i * 16 + l15) * NPB + n + k8 * 8];
#pragma unroll
        for (int j = 0; j < 2; j++)
            b[j] = *(const short8*)&krow[(size_t)(wc * 32 + j * 16 + l15) * NPB + n + k8 * 8];
        if (doq) {
#pragma unroll
            for (int i = 0; i < 2; i++)
#pragma unroll
                for (int u = 0; u < 8; u++) {
                    float f = bf2f((ushort)a[i][u]); sq[i] += f * f;
                }
        }
        if (dok) {
#pragma unroll
            for (int j = 0; j < 2; j++)
#pragma unroll
                for (int u = 0; u < 8; u++) {
                    float f = bf2f((ushort)b[j][u]); sk[j] += f * f;
                }
        }
#pragma unroll
        for (int i = 0; i < 2; i++)
#pragma unroll
            for (int j = 0; j < 2; j++)
                acc[i][j] = __builtin_amdgcn_mfma_f32_16x16x32_bf16(a[i], b[j], acc[i][j], 0, 0, 0);
    }
    float* S2o = S2 + ((size_t)ch * 64 + bh) * 192;
    if (doq) {
#pragma unroll
        for (int i = 0; i < 2; i++) {
            float v = sq[i];
            v += __shfl_xor(v, 16); v += __shfl_xor(v, 32);
            if (lane < 16) S2o[wr * 32 + i * 16 + l15] = v;
        }
    }
    if (dok) {
#pragma unroll
        for (int j = 0; j < 2; j++) {
            float v = sk[j];
            v += __shfl_xor(v, 16); v += __shfl_xor(v, 32);
            if (lane < 16) S2o[96 + wc * 32 + j * 16 + l15] = v;
        }
    }
    ushort* So = S + ((size_t)ch * 64 + bh) * (DH * DH);
#pragma unroll
    for (int i = 0; i < 2; i++)
#pragma unroll
        for (int j = 0; j < 2; j++) {
            int e = wc * 32 + j * 16 + l15;
#pragma unroll
            for (int qq = 0; qq < 4; qq++) {
                int d = wr * 32 + i * 16 + k8 * 4 + qq;
                So[d * DH + e] = f2bf(acc[i][j][qq]);
            }
        }
}

// ---------------- attn finish: chunk-reduce + softmax + W2 GEMM (fused) ----
__global__ __launch_bounds__(576) void attn_finish_kernel(
    const ushort* __restrict__ S, const float* __restrict__ S2,
    const float* __restrict__ temp, const ushort* __restrict__ pwb,
    ushort* __restrict__ W2) {
    int bh = blockIdx.x;
    int b_ = bh >> 3, h = bh & 7;
    int tid = threadIdx.x;
    __shared__ float rkv[96];
    __shared__ float red[96][6], red2[96][6];
    __shared__ ushort atl[96][104];   // [e][d], padded pitch
    int r = tid % 96, p = tid / 96;   // row d, col-group of 16
    if (tid < 96) {
        float sum = 0.f;
#pragma unroll 1
        for (int ch = 0; ch < 8; ch++)
            sum += S2[((size_t)ch * 64 + bh) * 192 + 96 + tid];
        rkv[tid] = 1.0f / fmaxf(sqrtf(sum), 1e-12f);
    }
    float sqd = 0.f;
#pragma unroll 1
    for (int ch = 0; ch < 8; ch++)
        sqd += S2[((size_t)ch * 64 + bh) * 192 + r];
    float rqd = 1.0f / fmaxf(sqrtf(sqd), 1e-12f);
    float v[16];
#pragma unroll
    for (int u = 0; u < 16; u++) v[u] = 0.f;
#pragma unroll 1
    for (int ch = 0; ch < 8; ch++) {
        const ushort* So = S + ((size_t)ch * 64 + bh) * (DH * DH) + r * DH + p * 16;
        short8 w0 = *(const short8*)So;
        short8 w1 = *(const short8*)(So + 8);
#pragma unroll
        for (int u = 0; u < 8; u++) {
            v[u] += bf2f((ushort)w0[u]);
            v[8 + u] += bf2f((ushort)w1[u]);
        }
    }
    __syncthreads();   // rkv ready
    float sd = rqd * temp[h];
#pragma unroll
    for (int u = 0; u < 16; u++) v[u] *= sd * rkv[p * 16 + u];
    float lm = v[0];
#pragma unroll
    for (int u = 1; u < 16; u++) lm = fmaxf(lm, v[u]);
    red[r][p] = lm;
    __syncthreads();
    float m = red[r][0];
#pragma unroll
    for (int u = 1; u < 6; u++) m = fmaxf(m, red[r][u]);
    float s = 0.f;
#pragma unroll
    for (int u = 0; u < 16; u++) { v[u] = __expf(v[u] - m); s += v[u]; }
    red2[r][p] = s;
    __syncthreads();
    float tot = red2[r][0];
#pragma unroll
    for (int u = 1; u < 6; u++) tot += red2[r][u];
    float inv = 1.0f / tot;
#pragma unroll
    for (int u = 0; u < 16; u++)
        atl[p * 16 + u][r] = f2bf(v[u] * inv);
    __syncthreads();
    // ---- Phase B: W2[b][o][h*96+e] = sum_d pw[o][h*96+d] * attn[d][e] ----
    int wid = tid >> 6, lane = tid & 63;
    if (wid < 8) {
        int k8 = lane >> 4, l15 = lane & 15;
        ushort* wo = W2 + (size_t)b_ * DIMC * DIMC + (size_t)h * DH;
#pragma unroll
        for (int pass = 0; pass < 2; pass++) {
            int o0 = wid * 96 + pass * 48;
            f32x4 acc[3][6] = {};
#pragma unroll
            for (int kk = 0; kk < DH; kk += 32) {
                short8 af[3], bf[6];
#pragma unroll
                for (int mm = 0; mm < 3; mm++)
                    af[mm] = *(const short8*)&pwb[(size_t)(o0 + mm * 16 + l15) * DIMC
                                                  + h * DH + kk + k8 * 8];
#pragma unroll
                for (int n = 0; n < 6; n++)
                    bf[n] = *(const short8*)&atl[n * 16 + l15][kk + k8 * 8];
#pragma unroll
                for (int mm = 0; mm < 3; mm++)
#pragma unroll
                    for (int n = 0; n < 6; n++)
                        acc[mm][n] = __builtin_amdgcn_mfma_f32_16x16x32_bf16(
                            af[mm], bf[n], acc[mm][n], 0, 0, 0);
            }
#pragma unroll
            for (int mm = 0; mm < 3; mm++) {
                int orow = o0 + mm * 16 + k8 * 4;
#pragma unroll
                for (int n = 0; n < 6; n++) {
                    int e = n * 16 + l15;
#pragma unroll
                    for (int qq = 0; qq < 4; qq++)
                        wo[(size_t)(orow + qq) * DIMC + e] = f2bf(acc[mm][n][qq]);
                }
            }
        }
    }
}

// ---------------- vproj: out = g1*(v·W2[b]^T + pb) + x  (128x256 core) -----
__global__ __launch_bounds__(512) void vproj_kernel(
    const ushort* __restrict__ vb, const ushort* __restrict__ W2,
    const float* __restrict__ pb, const float* __restrict__ g1,
    const float* __restrict__ x, float* __restrict__ out) {
    __shared__ __align__(16) char lds[49152];
    int orig = blockIdx.x;                   // 0..767
    int wg = (orig & 7) * 96 + (orig >> 3);
    int b_ = wg / 96, rem = wg % 96, mt = rem / 3, ntl = rem % 3;
    int tok0 = b_ * NPB + mt * 128, o0 = ntl * 256;
    f32x4 acc[4][4] = {};
    gemm128_core((const char*)(vb + (size_t)tok0 * DIMC),
                 (const char*)(W2 + (size_t)b_ * DIMC * DIMC + (size_t)o0 * DIMC),
                 lds, acc);

    const int tid = threadIdx.x;
    const int lane = tid & 63, wid = tid >> 6;
    const int wr = wid >> 2, wc = wid & 3;
    const int k8 = lane >> 4, l15 = lane & 15;
#pragma unroll
    for (int m8 = 0; m8 < 4; m8++) {
        int r0 = tok0 + wr * 64 + m8 * 16 + k8 * 4;
#pragma unroll
        for (int n = 0; n < 4; n++) {
            int o = o0 + wc * 64 + n * 16 + l15;
            float pbo = pb[o], g1o = g1[o];
            f32x4 a = acc[m8][n];
#pragma unroll
            for (int qq = 0; qq < 4; qq++) {
                size_t idx = (size_t)(r0 + qq) * DIMC + o;
                out[idx] = g1o * (a[qq] + pbo) + x[idx];
            }
        }
    }
}

extern "C" void kernel_launch(void* const* d_in, const int* in_sizes, int n_in,
                              void* d_out, int out_size, void* d_ws, size_t ws_size,
                              hipStream_t stream) {
    const float* x     = (const float*)d_in[0];
    const float* qkvw  = (const float*)d_in[1];
    const float* projw = (const float*)d_in[2];
    const float* projb = (const float*)d_in[3];
    const float* lng   = (const float*)d_in[4];
    const float* lnb   = (const float*)d_in[5];
    const float* temp  = (const float*)d_in[6];
    const float* g1    = (const float*)d_in[7];
    float* out = (float*)d_out;

    char* w = (char*)d_ws;
    ushort* qb    = (ushort*)(w + 0);            // 50,331,648  [B,H,dh,N]
    ushort* kb    = (ushort*)(w + 50331648);     // 50,331,648
    ushort* vb    = (ushort*)(w + 100663296);    // 50,331,648  [T, C] token-major
    ushort* qwb   = (ushort*)(w + 150994944);    // 3,538,944  (dead after qkv)
    ushort* pwb   = (ushort*)(w + 154533888);    // 1,179,648
    float*  S2    = (float*)(w + 155713536);     // 393,216 sumsq partials
    ushort* W2    = qb;                          // 9,437,184 (aliases dead qb)
    ushort* xb    = (ushort*)d_out;              // LN output (dead before vproj)
    ushort* Sb    = (ushort*)((char*)d_out + 50331648);  // 9.4 MB bf16 partials

    hipLaunchKernelGGL(prep_fused_kernel, dim3(9920), dim3(256), 0, stream,
                       qkvw, projw, qwb, pwb, x, lng, lnb, xb);
    hipLaunchKernelGGL(gemm_qkv_kernel, dim3(2304), dim3(512), 0, stream,
                       xb, qwb, qb, kb, vb);
    hipLaunchKernelGGL(attn_qk_kernel, dim3(64, 8), dim3(576), 0, stream,
                       qb, kb, Sb, S2);
    hipLaunchKernelGGL(attn_finish_kernel, dim3(64), dim3(576), 0, stream,
                       Sb, S2, temp, pwb, W2);
    hipLaunchKernelGGL(vproj_kernel, dim3(768), dim3(512), 0, stream,
                       vb, W2, projb, g1, x, out);
}